// Round 11
// baseline (201.203 us; speedup 1.0000x reference)
//
#include <hip/hip_runtime.h>
#include <math.h>

#define NN 50000
#define EE 600000
#define DD 128
#define KAPPA_C 0.95f
#define EPS_C 1e-5f
#define SCAN_BLK 1024
#define NB_SCAN ((NN + SCAN_BLK - 1) / SCAN_BLK)   // 49
#define NSLICE 8
#define SLICE_N ((NN + NSLICE - 1) / NSLICE)       // 6250
#define FCHUNK 192

typedef short s16x8 __attribute__((ext_vector_type(8)));   // 8 bf16 (4 VGPRs)
typedef float f32x4 __attribute__((ext_vector_type(4)));

__device__ __forceinline__ unsigned short f2bf(float f) {
    union { float f; unsigned int u; } v;
    v.f = f;
    unsigned int r = v.u + 0x7fffu + ((v.u >> 16) & 1u);
    return (unsigned short)(r >> 16);
}
__device__ __forceinline__ float bf2f(unsigned short b) {
    union { unsigned int u; float f; } v;
    v.u = ((unsigned int)b) << 16;
    return v.f;
}
__device__ __forceinline__ int2 ldcsr(const int2* p) {
    unsigned long long v = __builtin_nontemporal_load((const unsigned long long*)p);
    return make_int2((int)(unsigned int)(v & 0xffffffffull), (int)(unsigned int)(v >> 32));
}
// swizzled layout, element (r, k): (r>>4)*2048 + (k>>3)*128 + (r&15)*8 + (k&7)  [shorts]

// ---------------- W = Fm^T Fm, plus sum of squares ----------------
__global__ __launch_bounds__(128) void wmat_kernel(const float* __restrict__ Fm,
                                                   float* __restrict__ W,
                                                   float* __restrict__ ssq) {
    const int i = blockIdx.x;
    const int j = threadIdx.x;
    float acc = 0.f;
    #pragma unroll 8
    for (int k = 0; k < 128; ++k)
        acc += Fm[k * 128 + i] * Fm[k * 128 + j];
    W[i * 128 + j] = acc;
    __shared__ float red[128];
    red[j] = acc * acc;
    __syncthreads();
    for (int o = 64; o > 0; o >>= 1) {
        if (j < o) red[j] += red[j + o];
        __syncthreads();
    }
    if (j == 0) atomicAdd(ssq, red[0]);
}

// all three weight matrices -> swizzled split-bf16 (one dispatch, 192 blocks)
__global__ __launch_bounds__(256) void conv_weights(const float* __restrict__ W1,
                                                    const float* __restrict__ W2,
                                                    const float* __restrict__ Wmat,
                                                    const float* __restrict__ ssq,
                                                    unsigned short* __restrict__ W1th,
                                                    unsigned short* __restrict__ W1tl,
                                                    unsigned short* __restrict__ W2th,
                                                    unsigned short* __restrict__ W2tl,
                                                    unsigned short* __restrict__ Wmth,
                                                    unsigned short* __restrict__ Wmtl) {
    int b = blockIdx.x;
    const float* M;
    unsigned short *H, *L;
    float s = 1.0f;
    if (b < 64) { M = W1; H = W1th; L = W1tl; }
    else if (b < 128) { M = W2; H = W2th; L = W2tl; }
    else {
        M = Wmat; H = Wmth; L = Wmtl;
        float n = sqrtf(*ssq);
        s = ((n > 1.0f) ? 1.0f / (n + EPS_C) : 1.0f) * KAPPA_C;
    }
    int id = (b & 63) * 256 + threadIdx.x;       // id = k*128 + c
    float v = M[id] * s;
    int k = id >> 7, c = id & 127;
    size_t o = (size_t)(c >> 4) * 2048 + (size_t)(k >> 3) * 128 + (c & 15) * 8 + (k & 7);
    unsigned short h = f2bf(v);
    H[o] = h;
    L[o] = f2bf(v - bf2f(h));
}

// ---------------- conv: x AND emb f32 row-major -> bf16 swizzled (one dispatch) ----------------
__global__ __launch_bounds__(256) void conv2(const float* __restrict__ x,
                                             const float* __restrict__ emb,
                                             unsigned short* __restrict__ XS1,
                                             unsigned short* __restrict__ XS2) {
    const int half = NN / 16;            // 3125
    int t = blockIdx.x;
    const float* in = (t < half) ? x : emb;
    unsigned short* outp = (t < half) ? XS1 : XS2;
    if (t >= half) t -= half;
    const int rl = threadIdx.x >> 4;
    const int kq = threadIdx.x & 15;
    const float* xp = in + (size_t)(t * 16 + rl) * 128 + kq * 8;
    float4 f0 = ((const float4*)xp)[0];
    float4 f1 = ((const float4*)xp)[1];
    union { s16x8 v; unsigned short u[8]; } cv;
    cv.u[0] = f2bf(f0.x); cv.u[1] = f2bf(f0.y); cv.u[2] = f2bf(f0.z); cv.u[3] = f2bf(f0.w);
    cv.u[4] = f2bf(f1.x); cv.u[5] = f2bf(f1.y); cv.u[6] = f2bf(f1.z); cv.u[7] = f2bf(f1.w);
    *(s16x8*)(outp + (size_t)t * 2048 + (size_t)kq * 128 + rl * 8) = cv.v;
}

// ---------------- CSR build (XCD-sliced) ----------------
__global__ __launch_bounds__(256) void hist_kernel(const int* __restrict__ dst,
                                                   int* __restrict__ counts) {
    const int slice = blockIdx.x & (NSLICE - 1);
    const int lo = slice * SLICE_N;
    const int hi = lo + SLICE_N;
    const int chunk = blockIdx.x >> 3;
    const int per = (EE + FCHUNK - 1) / FCHUNK;
    const int e0 = chunk * per;
    int e1 = e0 + per; if (e1 > EE) e1 = EE;
    for (int e = e0 + threadIdx.x; e < e1; e += 256) {
        int d = __builtin_nontemporal_load(&dst[e]);
        if (d >= lo && d < hi) atomicAdd(&counts[d], 1);
    }
}

__global__ __launch_bounds__(SCAN_BLK) void scan_blocks(const int* __restrict__ counts,
                                                        int* __restrict__ rs,
                                                        int* __restrict__ bsum) {
    __shared__ int sd[SCAN_BLK];
    int tid = threadIdx.x;
    int gid = blockIdx.x * SCAN_BLK + tid;
    int v = (gid < NN) ? counts[gid] : 0;
    sd[tid] = v;
    __syncthreads();
    for (int o = 1; o < SCAN_BLK; o <<= 1) {
        int t = (tid >= o) ? sd[tid - o] : 0;
        __syncthreads();
        sd[tid] += t;
        __syncthreads();
    }
    if (gid < NN) rs[gid] = sd[tid] - v;
    if (tid == SCAN_BLK - 1) bsum[blockIdx.x] = sd[tid];
}

__global__ __launch_bounds__(SCAN_BLK) void scan_add(int* __restrict__ rs,
                                                     const int* __restrict__ bsum) {
    __shared__ int pre;
    if (threadIdx.x == 0) {
        int run = 0;
        for (int i = 0; i < (int)blockIdx.x; ++i) run += bsum[i];
        pre = run;
    }
    __syncthreads();
    int gid = blockIdx.x * SCAN_BLK + threadIdx.x;
    if (gid < NN) rs[gid] += pre;
    if (gid == NN - 1) rs[NN] = EE;
}

__global__ __launch_bounds__(256) void fill_kernel(const int* __restrict__ src,
                                                   const int* __restrict__ dst,
                                                   const float* __restrict__ w,
                                                   const int* __restrict__ rs,
                                                   int* __restrict__ cursor,
                                                   int2* __restrict__ csr) {
    const int slice = blockIdx.x & (NSLICE - 1);
    const int lo = slice * SLICE_N;
    const int hi = lo + SLICE_N;
    const int chunk = blockIdx.x >> 3;
    const int per = (EE + FCHUNK - 1) / FCHUNK;
    const int e0 = chunk * per;
    int e1 = e0 + per; if (e1 > EE) e1 = EE;
    for (int e = e0 + threadIdx.x; e < e1; e += 256) {
        int d = __builtin_nontemporal_load(&dst[e]);
        if (d >= lo && d < hi) {
            int pos = atomicAdd(&cursor[d], 1);
            csr[rs[d] + pos] = make_int2(__builtin_nontemporal_load(&src[e]),
                                         __float_as_int(__builtin_nontemporal_load(&w[e])));
        }
    }
}

// ---------------- MFMA GEMM: swizzled bf16 A and B, 32-row tile, out row-major bf16 ----------------
__global__ __launch_bounds__(256, 4) void gemm_mfma(const unsigned short* __restrict__ Xs,
                                                    const unsigned short* __restrict__ Mth,
                                                    const unsigned short* __restrict__ Mtl,
                                                    unsigned short* __restrict__ outh,
                                                    int nrows) {
    const int wave = threadIdx.x >> 6;
    const int lane = threadIdx.x & 63;
    const int row0 = blockIdx.x * 32;
    const int col0 = wave * 32;
    const int lr = lane & 15;
    const int kg = lane >> 4;
    const int lastT = nrows / 16 - 1;

    f32x4 acc[2][2];
    #pragma unroll
    for (int m = 0; m < 2; ++m)
        #pragma unroll
        for (int n = 0; n < 2; ++n)
            acc[m][n] = (f32x4){0.f, 0.f, 0.f, 0.f};

    #pragma unroll
    for (int k0 = 0; k0 < 128; k0 += 32) {
        const int kq = (k0 >> 3) + kg;
        s16x8 a[2];
        #pragma unroll
        for (int m = 0; m < 2; ++m) {
            int t = (row0 >> 4) + m;
            if (t > lastT) t = lastT;
            a[m] = *(const s16x8*)(Xs + (size_t)t * 2048 + (size_t)kq * 128 + lr * 8);
        }
        #pragma unroll
        for (int n = 0; n < 2; ++n) {
            const size_t bo = (size_t)((col0 >> 4) + n) * 2048 + (size_t)kq * 128 + lr * 8;
            s16x8 bh = *(const s16x8*)(Mth + bo);
            s16x8 bl = *(const s16x8*)(Mtl + bo);
            #pragma unroll
            for (int m = 0; m < 2; ++m) {
                acc[m][n] = __builtin_amdgcn_mfma_f32_16x16x32_bf16(a[m], bh, acc[m][n], 0, 0, 0);
                acc[m][n] = __builtin_amdgcn_mfma_f32_16x16x32_bf16(a[m], bl, acc[m][n], 0, 0, 0);
            }
        }
    }

    #pragma unroll
    for (int m = 0; m < 2; ++m)
        #pragma unroll
        for (int n = 0; n < 2; ++n)
            #pragma unroll
            for (int j = 0; j < 4; ++j) {
                int r = row0 + m * 16 + kg * 4 + j;
                int c = col0 + n * 16 + lr;
                if (r < nrows)
                    outh[(size_t)r * 128 + c] = f2bf(acc[m][n][j]);
            }
}

// ---------------- dual GEMM: P = bf16( H@W2 + emb@Wm' ), all operands swizzled ----------------
__global__ __launch_bounds__(256, 4) void gemm_pe(const unsigned short* __restrict__ Hs,
                                                  const unsigned short* __restrict__ Es,
                                                  const unsigned short* __restrict__ W2th,
                                                  const unsigned short* __restrict__ W2tl,
                                                  const unsigned short* __restrict__ Wmth,
                                                  const unsigned short* __restrict__ Wmtl,
                                                  unsigned short* __restrict__ P,
                                                  int nrows) {
    const int wave = threadIdx.x >> 6;
    const int lane = threadIdx.x & 63;
    const int row0 = blockIdx.x * 32;
    const int col0 = wave * 32;
    const int lr = lane & 15;
    const int kg = lane >> 4;
    const int lastT = nrows / 16 - 1;

    f32x4 acc[2][2];
    #pragma unroll
    for (int m = 0; m < 2; ++m)
        #pragma unroll
        for (int n = 0; n < 2; ++n)
            acc[m][n] = (f32x4){0.f, 0.f, 0.f, 0.f};

    #pragma unroll
    for (int k0 = 0; k0 < 128; k0 += 32) {
        const int kq = (k0 >> 3) + kg;
        s16x8 ah[2], ae[2];
        #pragma unroll
        for (int m = 0; m < 2; ++m) {
            int t = (row0 >> 4) + m;
            if (t > lastT) t = lastT;
            const size_t ao = (size_t)t * 2048 + (size_t)kq * 128 + lr * 8;
            ah[m] = *(const s16x8*)(Hs + ao);
            ae[m] = *(const s16x8*)(Es + ao);
        }
        #pragma unroll
        for (int n = 0; n < 2; ++n) {
            const size_t bo = (size_t)((col0 >> 4) + n) * 2048 + (size_t)kq * 128 + lr * 8;
            s16x8 b2h = *(const s16x8*)(W2th + bo);
            s16x8 b2l = *(const s16x8*)(W2tl + bo);
            s16x8 bmh = *(const s16x8*)(Wmth + bo);
            s16x8 bml = *(const s16x8*)(Wmtl + bo);
            #pragma unroll
            for (int m = 0; m < 2; ++m) {
                acc[m][n] = __builtin_amdgcn_mfma_f32_16x16x32_bf16(ah[m], b2h, acc[m][n], 0, 0, 0);
                acc[m][n] = __builtin_amdgcn_mfma_f32_16x16x32_bf16(ah[m], b2l, acc[m][n], 0, 0, 0);
                acc[m][n] = __builtin_amdgcn_mfma_f32_16x16x32_bf16(ae[m], bmh, acc[m][n], 0, 0, 0);
                acc[m][n] = __builtin_amdgcn_mfma_f32_16x16x32_bf16(ae[m], bml, acc[m][n], 0, 0, 0);
            }
        }
    }

    #pragma unroll
    for (int m = 0; m < 2; ++m)
        #pragma unroll
        for (int n = 0; n < 2; ++n)
            #pragma unroll
            for (int j = 0; j < 4; ++j) {
                int r = row0 + m * 16 + kg * 4 + j;
                int c = col0 + n * 16 + lr;
                if (r < nrows)
                    P[(size_t)r * 128 + c] = f2bf(acc[m][n][j]);
            }
}

// ---------------- SpMM v2: 1 node/wave, 16 lanes/row, 4 edge-slots, 4-deep unroll ----------------
// RELU=1: out = swizzled bf16 relu(acc + bias);  RELU=0: out = f32 row-major acc + bias.
template <int RELU>
__global__ __launch_bounds__(256) void spmm_v2(const unsigned short* __restrict__ P,
                                               const int* __restrict__ rs,
                                               const int2* __restrict__ csr,
                                               const float* __restrict__ bias,
                                               unsigned short* __restrict__ outh,
                                               float* __restrict__ outf) {
    const int node = blockIdx.x * 4 + (threadIdx.x >> 6);
    const int lane = threadIdx.x & 63;
    const int chunk = lane & 15;         // 8 channels: [chunk*8, chunk*8+8)
    const int slot = lane >> 4;          // edge slot 0..3
    const int re = rs[node + 1];

    float acc[8];
    #pragma unroll
    for (int j = 0; j < 8; ++j) acc[j] = 0.f;

    for (int e = rs[node] + slot; e < re; e += 16) {
        {
            int2 p = ldcsr(&csr[e]);
            float w = __int_as_float(p.y);
            s16x8 v = *(const s16x8*)(P + (size_t)p.x * 128 + chunk * 8);
            #pragma unroll
            for (int j = 0; j < 8; ++j) acc[j] += w * bf2f((unsigned short)v[j]);
        }
        if (e + 4 < re) {
            int2 p = ldcsr(&csr[e + 4]);
            float w = __int_as_float(p.y);
            s16x8 v = *(const s16x8*)(P + (size_t)p.x * 128 + chunk * 8);
            #pragma unroll
            for (int j = 0; j < 8; ++j) acc[j] += w * bf2f((unsigned short)v[j]);
        }
        if (e + 8 < re) {
            int2 p = ldcsr(&csr[e + 8]);
            float w = __int_as_float(p.y);
            s16x8 v = *(const s16x8*)(P + (size_t)p.x * 128 + chunk * 8);
            #pragma unroll
            for (int j = 0; j < 8; ++j) acc[j] += w * bf2f((unsigned short)v[j]);
        }
        if (e + 12 < re) {
            int2 p = ldcsr(&csr[e + 12]);
            float w = __int_as_float(p.y);
            s16x8 v = *(const s16x8*)(P + (size_t)p.x * 128 + chunk * 8);
            #pragma unroll
            for (int j = 0; j < 8; ++j) acc[j] += w * bf2f((unsigned short)v[j]);
        }
    }

    // combine the 4 slots (lanes with equal chunk): xor 16, xor 32
    #pragma unroll
    for (int j = 0; j < 8; ++j) {
        acc[j] += __shfl_xor(acc[j], 16);
        acc[j] += __shfl_xor(acc[j], 32);
    }

    if (lane < 16) {
        float4 b0 = ((const float4*)bias)[chunk * 2];
        float4 b1v = ((const float4*)bias)[chunk * 2 + 1];
        float r0 = acc[0] + b0.x, r1 = acc[1] + b0.y, r2 = acc[2] + b0.z, r3 = acc[3] + b0.w;
        float r4 = acc[4] + b1v.x, r5 = acc[5] + b1v.y, r6 = acc[6] + b1v.z, r7 = acc[7] + b1v.w;
        if (RELU) {
            union { s16x8 v; unsigned short u[8]; } o;
            o.u[0] = f2bf(fmaxf(r0, 0.f)); o.u[1] = f2bf(fmaxf(r1, 0.f));
            o.u[2] = f2bf(fmaxf(r2, 0.f)); o.u[3] = f2bf(fmaxf(r3, 0.f));
            o.u[4] = f2bf(fmaxf(r4, 0.f)); o.u[5] = f2bf(fmaxf(r5, 0.f));
            o.u[6] = f2bf(fmaxf(r6, 0.f)); o.u[7] = f2bf(fmaxf(r7, 0.f));
            // swizzled store for row=node, k=chunk*8..+8
            size_t so = (size_t)(node >> 4) * 2048 + (size_t)chunk * 128 + (node & 15) * 8;
            *(s16x8*)(outh + so) = o.v;
        } else {
            float* op = outf + (size_t)node * 128 + chunk * 8;
            ((float4*)op)[0] = make_float4(r0, r1, r2, r3);
            ((float4*)op)[1] = make_float4(r4, r5, r6, r7);
        }
    }
}

static inline size_t align_up(size_t x, size_t a) { return (x + a - 1) / a * a; }

extern "C" void kernel_launch(void* const* d_in, const int* in_sizes, int n_in,
                              void* d_out, int out_size, void* d_ws, size_t ws_size,
                              hipStream_t stream) {
    const float* x   = (const float*)d_in[0];
    const int*   esrc = (const int*)d_in[1];
    const int*   edst = (const int*)d_in[2];
    const float* ew  = (const float*)d_in[3];
    const float* W1  = (const float*)d_in[4];
    const float* b1  = (const float*)d_in[5];
    const float* W2  = (const float*)d_in[6];
    const float* b2  = (const float*)d_in[7];
    const float* Fm  = (const float*)d_in[8];
    const float* emb = (const float*)d_in[9];
    float* out = (float*)d_out;

    char* ws = (char*)d_ws;
    size_t off = 0;
    auto alloc = [&](size_t bytes) -> void* {
        void* p = ws + off;
        off = align_up(off + bytes, 256);
        return p;
    };
    unsigned short* B1  = (unsigned short*)alloc((size_t)NN * DD * 2);   // 12.8 MB: h1 row-major, then P
    unsigned short* XS1 = (unsigned short*)alloc((size_t)NN * DD * 2);   // 12.8 MB: swizzled x
    unsigned short* XS2 = (unsigned short*)alloc((size_t)NN * DD * 2);   // 12.8 MB: swizzled emb
    float* Wmat   = (float*)alloc(128 * 128 * 4);
    int*   counts = (int*)alloc((size_t)NN * 4);
    int*   cursor = (int*)alloc((size_t)NN * 4);
    float* ssq    = (float*)alloc(256);
    int*   rs     = (int*)alloc((size_t)(NN + 1) * 4);
    int*   bsum   = (int*)alloc(64 * 4);
    int2*  csr    = (int2*)alloc((size_t)EE * 8);                        // 4.8 MB
    unsigned short* W1th = (unsigned short*)alloc(128 * 128 * 2);
    unsigned short* W1tl = (unsigned short*)alloc(128 * 128 * 2);
    unsigned short* W2th = (unsigned short*)alloc(128 * 128 * 2);
    unsigned short* W2tl = (unsigned short*)alloc(128 * 128 * 2);
    unsigned short* Wmth = (unsigned short*)alloc(128 * 128 * 2);
    unsigned short* Wmtl = (unsigned short*)alloc(128 * 128 * 2);
    if (off > ws_size) return;

    // H (relu output, swizzled bf16, 12.8 MB) lives in d_out's bytes;
    // dead after gemm_pe reads it, before spmm_final writes out.
    unsigned short* H = (unsigned short*)d_out;

    // zero [counts | cursor | ssq]
    size_t zero_bytes = (size_t)((char*)ssq - (char*)counts) + 256;
    hipMemsetAsync(counts, 0, zero_bytes, stream);

    // projection matrix + all weight conversions
    wmat_kernel<<<128, 128, 0, stream>>>(Fm, Wmat, ssq);
    conv_weights<<<192, 256, 0, stream>>>(W1, W2, Wmat, ssq,
                                          W1th, W1tl, W2th, W2tl, Wmth, Wmtl);

    // CSR build (XCD-sliced)
    const int sgrid = NSLICE * FCHUNK;   // 1536
    hist_kernel<<<sgrid, 256, 0, stream>>>(edst, counts);
    scan_blocks<<<NB_SCAN, SCAN_BLK, 0, stream>>>(counts, rs, bsum);
    scan_add<<<NB_SCAN, SCAN_BLK, 0, stream>>>(rs, bsum);
    fill_kernel<<<sgrid, 256, 0, stream>>>(esrc, edst, ew, rs, cursor, csr);

    // x and emb -> swizzled bf16 (one dispatch)
    conv2<<<2 * (NN / 16), 256, 0, stream>>>(x, emb, XS1, XS2);

    const int gemm_grid = (NN + 31) / 32;     // 1563
    const int spmm_grid = NN / 4;             // 12500

    // h1 = bf16(x @ W1) -> B1 (row-major)
    gemm_mfma<<<gemm_grid, 256, 0, stream>>>(XS1, W1th, W1tl, B1, NN);
    // h = relu(A @ h1 + b1) -> H swizzled (in d_out bytes)
    spmm_v2<1><<<spmm_grid, 256, 0, stream>>>(B1, rs, csr, b1, H, nullptr);
    // P = bf16(h @ W2 + emb @ Wm') -> B1 (row-major; h1 dead)
    gemm_pe<<<gemm_grid, 256, 0, stream>>>(H, XS2, W2th, W2tl, Wmth, Wmtl, B1, NN);
    // out = A @ P + b2
    spmm_v2<0><<<spmm_grid, 256, 0, stream>>>(B1, rs, csr, b2, nullptr, out);
}

// Round 12
// 183.651 us; speedup vs baseline: 1.0956x; 1.0956x over previous
//
#include <hip/hip_runtime.h>
#include <math.h>

#define NN 50000
#define EE 600000
#define DD 128
#define KAPPA_C 0.95f
#define EPS_C 1e-5f
#define SCAN_BLK 1024
#define NB_SCAN ((NN + SCAN_BLK - 1) / SCAN_BLK)   // 49
#define NSLICE 8
#define SLICE_N ((NN + NSLICE - 1) / NSLICE)       // 6250
#define FCHUNK 192

typedef short s16x8 __attribute__((ext_vector_type(8)));   // 8 bf16 (4 VGPRs)
typedef float f32x4 __attribute__((ext_vector_type(4)));

__device__ __forceinline__ unsigned short f2bf(float f) {
    union { float f; unsigned int u; } v;
    v.f = f;
    unsigned int r = v.u + 0x7fffu + ((v.u >> 16) & 1u);
    return (unsigned short)(r >> 16);
}
__device__ __forceinline__ float bf2f(unsigned short b) {
    union { unsigned int u; float f; } v;
    v.u = ((unsigned int)b) << 16;
    return v.f;
}
// swizzled layout, element (r, k): (r>>4)*2048 + (k>>3)*128 + (r&15)*8 + (k&7)  [shorts]

// ---------------- W = Fm^T Fm, plus sum of squares ----------------
__global__ __launch_bounds__(128) void wmat_kernel(const float* __restrict__ Fm,
                                                   float* __restrict__ W,
                                                   float* __restrict__ ssq) {
    const int i = blockIdx.x;
    const int j = threadIdx.x;
    float acc = 0.f;
    #pragma unroll 8
    for (int k = 0; k < 128; ++k)
        acc += Fm[k * 128 + i] * Fm[k * 128 + j];
    W[i * 128 + j] = acc;
    __shared__ float red[128];
    red[j] = acc * acc;
    __syncthreads();
    for (int o = 64; o > 0; o >>= 1) {
        if (j < o) red[j] += red[j + o];
        __syncthreads();
    }
    if (j == 0) atomicAdd(ssq, red[0]);
}

// all three weight matrices -> swizzled split-bf16 (one dispatch, 192 blocks)
__global__ __launch_bounds__(256) void conv_weights(const float* __restrict__ W1,
                                                    const float* __restrict__ W2,
                                                    const float* __restrict__ Wmat,
                                                    const float* __restrict__ ssq,
                                                    unsigned short* __restrict__ W1th,
                                                    unsigned short* __restrict__ W1tl,
                                                    unsigned short* __restrict__ W2th,
                                                    unsigned short* __restrict__ W2tl,
                                                    unsigned short* __restrict__ Wmth,
                                                    unsigned short* __restrict__ Wmtl) {
    int b = blockIdx.x;
    const float* M;
    unsigned short *H, *L;
    float s = 1.0f;
    if (b < 64) { M = W1; H = W1th; L = W1tl; }
    else if (b < 128) { M = W2; H = W2th; L = W2tl; }
    else {
        M = Wmat; H = Wmth; L = Wmtl;
        float n = sqrtf(*ssq);
        s = ((n > 1.0f) ? 1.0f / (n + EPS_C) : 1.0f) * KAPPA_C;
    }
    int id = (b & 63) * 256 + threadIdx.x;       // id = k*128 + c
    float v = M[id] * s;
    int k = id >> 7, c = id & 127;
    size_t o = (size_t)(c >> 4) * 2048 + (size_t)(k >> 3) * 128 + (c & 15) * 8 + (k & 7);
    unsigned short h = f2bf(v);
    H[o] = h;
    L[o] = f2bf(v - bf2f(h));
}

// ---------------- conv: x AND emb f32 row-major -> bf16 swizzled (one dispatch) ----------------
__global__ __launch_bounds__(256) void conv2(const float* __restrict__ x,
                                             const float* __restrict__ emb,
                                             unsigned short* __restrict__ XS1,
                                             unsigned short* __restrict__ XS2) {
    const int half = NN / 16;            // 3125
    int t = blockIdx.x;
    const float* in = (t < half) ? x : emb;
    unsigned short* outp = (t < half) ? XS1 : XS2;
    if (t >= half) t -= half;
    const int rl = threadIdx.x >> 4;
    const int kq = threadIdx.x & 15;
    const float* xp = in + (size_t)(t * 16 + rl) * 128 + kq * 8;
    float4 f0 = ((const float4*)xp)[0];
    float4 f1 = ((const float4*)xp)[1];
    union { s16x8 v; unsigned short u[8]; } cv;
    cv.u[0] = f2bf(f0.x); cv.u[1] = f2bf(f0.y); cv.u[2] = f2bf(f0.z); cv.u[3] = f2bf(f0.w);
    cv.u[4] = f2bf(f1.x); cv.u[5] = f2bf(f1.y); cv.u[6] = f2bf(f1.z); cv.u[7] = f2bf(f1.w);
    *(s16x8*)(outp + (size_t)t * 2048 + (size_t)kq * 128 + rl * 8) = cv.v;
}

// ---------------- CSR build (XCD-sliced) ----------------
__global__ __launch_bounds__(256) void hist_kernel(const int* __restrict__ dst,
                                                   int* __restrict__ counts) {
    const int slice = blockIdx.x & (NSLICE - 1);
    const int lo = slice * SLICE_N;
    const int hi = lo + SLICE_N;
    const int chunk = blockIdx.x >> 3;
    const int per = (EE + FCHUNK - 1) / FCHUNK;
    const int e0 = chunk * per;
    int e1 = e0 + per; if (e1 > EE) e1 = EE;
    for (int e = e0 + threadIdx.x; e < e1; e += 256) {
        int d = __builtin_nontemporal_load(&dst[e]);
        if (d >= lo && d < hi) atomicAdd(&counts[d], 1);
    }
}

__global__ __launch_bounds__(SCAN_BLK) void scan_blocks(const int* __restrict__ counts,
                                                        int* __restrict__ rs,
                                                        int* __restrict__ bsum) {
    __shared__ int sd[SCAN_BLK];
    int tid = threadIdx.x;
    int gid = blockIdx.x * SCAN_BLK + tid;
    int v = (gid < NN) ? counts[gid] : 0;
    sd[tid] = v;
    __syncthreads();
    for (int o = 1; o < SCAN_BLK; o <<= 1) {
        int t = (tid >= o) ? sd[tid - o] : 0;
        __syncthreads();
        sd[tid] += t;
        __syncthreads();
    }
    if (gid < NN) rs[gid] = sd[tid] - v;
    if (tid == SCAN_BLK - 1) bsum[blockIdx.x] = sd[tid];
}

__global__ __launch_bounds__(SCAN_BLK) void scan_add(int* __restrict__ rs,
                                                     const int* __restrict__ bsum) {
    __shared__ int pre;
    if (threadIdx.x == 0) {
        int run = 0;
        for (int i = 0; i < (int)blockIdx.x; ++i) run += bsum[i];
        pre = run;
    }
    __syncthreads();
    int gid = blockIdx.x * SCAN_BLK + threadIdx.x;
    if (gid < NN) rs[gid] += pre;
    if (gid == NN - 1) rs[NN] = EE;
}

__global__ __launch_bounds__(256) void fill_kernel(const int* __restrict__ src,
                                                   const int* __restrict__ dst,
                                                   const float* __restrict__ w,
                                                   const int* __restrict__ rs,
                                                   int* __restrict__ cursor,
                                                   int2* __restrict__ csr) {
    const int slice = blockIdx.x & (NSLICE - 1);
    const int lo = slice * SLICE_N;
    const int hi = lo + SLICE_N;
    const int chunk = blockIdx.x >> 3;
    const int per = (EE + FCHUNK - 1) / FCHUNK;
    const int e0 = chunk * per;
    int e1 = e0 + per; if (e1 > EE) e1 = EE;
    for (int e = e0 + threadIdx.x; e < e1; e += 256) {
        int d = __builtin_nontemporal_load(&dst[e]);
        if (d >= lo && d < hi) {
            int pos = atomicAdd(&cursor[d], 1);
            csr[rs[d] + pos] = make_int2(__builtin_nontemporal_load(&src[e]),
                                         __float_as_int(__builtin_nontemporal_load(&w[e])));
        }
    }
}

// ---------------- MFMA GEMM: swizzled bf16 A and B, 32-row tile, out row-major bf16 ----------------
__global__ __launch_bounds__(256, 4) void gemm_mfma(const unsigned short* __restrict__ Xs,
                                                    const unsigned short* __restrict__ Mth,
                                                    const unsigned short* __restrict__ Mtl,
                                                    unsigned short* __restrict__ outh,
                                                    int nrows) {
    const int wave = threadIdx.x >> 6;
    const int lane = threadIdx.x & 63;
    const int row0 = blockIdx.x * 32;
    const int col0 = wave * 32;
    const int lr = lane & 15;
    const int kg = lane >> 4;
    const int lastT = nrows / 16 - 1;

    f32x4 acc[2][2];
    #pragma unroll
    for (int m = 0; m < 2; ++m)
        #pragma unroll
        for (int n = 0; n < 2; ++n)
            acc[m][n] = (f32x4){0.f, 0.f, 0.f, 0.f};

    #pragma unroll
    for (int k0 = 0; k0 < 128; k0 += 32) {
        const int kq = (k0 >> 3) + kg;
        s16x8 a[2];
        #pragma unroll
        for (int m = 0; m < 2; ++m) {
            int t = (row0 >> 4) + m;
            if (t > lastT) t = lastT;
            a[m] = *(const s16x8*)(Xs + (size_t)t * 2048 + (size_t)kq * 128 + lr * 8);
        }
        #pragma unroll
        for (int n = 0; n < 2; ++n) {
            const size_t bo = (size_t)((col0 >> 4) + n) * 2048 + (size_t)kq * 128 + lr * 8;
            s16x8 bh = *(const s16x8*)(Mth + bo);
            s16x8 bl = *(const s16x8*)(Mtl + bo);
            #pragma unroll
            for (int m = 0; m < 2; ++m) {
                acc[m][n] = __builtin_amdgcn_mfma_f32_16x16x32_bf16(a[m], bh, acc[m][n], 0, 0, 0);
                acc[m][n] = __builtin_amdgcn_mfma_f32_16x16x32_bf16(a[m], bl, acc[m][n], 0, 0, 0);
            }
        }
    }

    #pragma unroll
    for (int m = 0; m < 2; ++m)
        #pragma unroll
        for (int n = 0; n < 2; ++n)
            #pragma unroll
            for (int j = 0; j < 4; ++j) {
                int r = row0 + m * 16 + kg * 4 + j;
                int c = col0 + n * 16 + lr;
                if (r < nrows)
                    outh[(size_t)r * 128 + c] = f2bf(acc[m][n][j]);
            }
}

// ---------------- dual GEMM: P = bf16( H@W2 + emb@Wm' ), all operands swizzled ----------------
__global__ __launch_bounds__(256, 4) void gemm_pe(const unsigned short* __restrict__ Hs,
                                                  const unsigned short* __restrict__ Es,
                                                  const unsigned short* __restrict__ W2th,
                                                  const unsigned short* __restrict__ W2tl,
                                                  const unsigned short* __restrict__ Wmth,
                                                  const unsigned short* __restrict__ Wmtl,
                                                  unsigned short* __restrict__ P,
                                                  int nrows) {
    const int wave = threadIdx.x >> 6;
    const int lane = threadIdx.x & 63;
    const int row0 = blockIdx.x * 32;
    const int col0 = wave * 32;
    const int lr = lane & 15;
    const int kg = lane >> 4;
    const int lastT = nrows / 16 - 1;

    f32x4 acc[2][2];
    #pragma unroll
    for (int m = 0; m < 2; ++m)
        #pragma unroll
        for (int n = 0; n < 2; ++n)
            acc[m][n] = (f32x4){0.f, 0.f, 0.f, 0.f};

    #pragma unroll
    for (int k0 = 0; k0 < 128; k0 += 32) {
        const int kq = (k0 >> 3) + kg;
        s16x8 ah[2], ae[2];
        #pragma unroll
        for (int m = 0; m < 2; ++m) {
            int t = (row0 >> 4) + m;
            if (t > lastT) t = lastT;
            const size_t ao = (size_t)t * 2048 + (size_t)kq * 128 + lr * 8;
            ah[m] = *(const s16x8*)(Hs + ao);
            ae[m] = *(const s16x8*)(Es + ao);
        }
        #pragma unroll
        for (int n = 0; n < 2; ++n) {
            const size_t bo = (size_t)((col0 >> 4) + n) * 2048 + (size_t)kq * 128 + lr * 8;
            s16x8 b2h = *(const s16x8*)(W2th + bo);
            s16x8 b2l = *(const s16x8*)(W2tl + bo);
            s16x8 bmh = *(const s16x8*)(Wmth + bo);
            s16x8 bml = *(const s16x8*)(Wmtl + bo);
            #pragma unroll
            for (int m = 0; m < 2; ++m) {
                acc[m][n] = __builtin_amdgcn_mfma_f32_16x16x32_bf16(ah[m], b2h, acc[m][n], 0, 0, 0);
                acc[m][n] = __builtin_amdgcn_mfma_f32_16x16x32_bf16(ah[m], b2l, acc[m][n], 0, 0, 0);
                acc[m][n] = __builtin_amdgcn_mfma_f32_16x16x32_bf16(ae[m], bmh, acc[m][n], 0, 0, 0);
                acc[m][n] = __builtin_amdgcn_mfma_f32_16x16x32_bf16(ae[m], bml, acc[m][n], 0, 0, 0);
            }
        }
    }

    #pragma unroll
    for (int m = 0; m < 2; ++m)
        #pragma unroll
        for (int n = 0; n < 2; ++n)
            #pragma unroll
            for (int j = 0; j < 4; ++j) {
                int r = row0 + m * 16 + kg * 4 + j;
                int c = col0 + n * 16 + lr;
                if (r < nrows)
                    P[(size_t)r * 128 + c] = f2bf(acc[m][n][j]);
            }
}

// ---------------- SpMM 1: h = relu(A @ h1 + b1); row-major gather, SWIZZLED bf16 out ----------------
__global__ __launch_bounds__(256) void spmm_relu(const unsigned short* __restrict__ h,
                                                 const int* __restrict__ rs,
                                                 const int2* __restrict__ csr,
                                                 const float* __restrict__ bias,
                                                 unsigned short* __restrict__ Hs) {
    int node = blockIdx.x * 8 + (threadIdx.x >> 5);
    int lane = threadIdx.x & 31;
    if (node >= NN) return;
    int e = rs[node];
    const int re = rs[node + 1];
    float4 acc = make_float4(0.f, 0.f, 0.f, 0.f);
    for (; e + 3 < re; e += 4) {
        int2 p0 = csr[e];
        int2 p1 = csr[e + 1];
        int2 p2 = csr[e + 2];
        int2 p3 = csr[e + 3];
        ushort4 v0 = *(const ushort4*)(h + (size_t)p0.x * 128 + lane * 4);
        ushort4 v1 = *(const ushort4*)(h + (size_t)p1.x * 128 + lane * 4);
        ushort4 v2 = *(const ushort4*)(h + (size_t)p2.x * 128 + lane * 4);
        ushort4 v3 = *(const ushort4*)(h + (size_t)p3.x * 128 + lane * 4);
        float w0 = __int_as_float(p0.y), w1 = __int_as_float(p1.y);
        float w2 = __int_as_float(p2.y), w3 = __int_as_float(p3.y);
        acc.x += w0 * bf2f(v0.x) + w1 * bf2f(v1.x) + w2 * bf2f(v2.x) + w3 * bf2f(v3.x);
        acc.y += w0 * bf2f(v0.y) + w1 * bf2f(v1.y) + w2 * bf2f(v2.y) + w3 * bf2f(v3.y);
        acc.z += w0 * bf2f(v0.z) + w1 * bf2f(v1.z) + w2 * bf2f(v2.z) + w3 * bf2f(v3.z);
        acc.w += w0 * bf2f(v0.w) + w1 * bf2f(v1.w) + w2 * bf2f(v2.w) + w3 * bf2f(v3.w);
    }
    for (; e < re; ++e) {
        int2 p0 = csr[e];
        float w0 = __int_as_float(p0.y);
        ushort4 v0 = *(const ushort4*)(h + (size_t)p0.x * 128 + lane * 4);
        acc.x += w0 * bf2f(v0.x); acc.y += w0 * bf2f(v0.y);
        acc.z += w0 * bf2f(v0.z); acc.w += w0 * bf2f(v0.w);
    }
    float4 b = ((const float4*)bias)[lane];
    acc.x = fmaxf(acc.x + b.x, 0.f); acc.y = fmaxf(acc.y + b.y, 0.f);
    acc.z = fmaxf(acc.z + b.z, 0.f); acc.w = fmaxf(acc.w + b.w, 0.f);
    ushort4 o;
    o.x = f2bf(acc.x); o.y = f2bf(acc.y); o.z = f2bf(acc.z); o.w = f2bf(acc.w);
    // swizzled store: element (node, k=lane*4..+4)
    size_t so = (size_t)(node >> 4) * 2048 + (size_t)(lane >> 1) * 128
              + (node & 15) * 8 + (lane & 1) * 4;
    *(ushort4*)(Hs + so) = o;
}

// ---------------- final SpMM: out = A@P + b2 (f32 out), row-major gather ----------------
__global__ __launch_bounds__(256) void spmm_final(const unsigned short* __restrict__ P,
                                                  const int* __restrict__ rs,
                                                  const int2* __restrict__ csr,
                                                  const float* __restrict__ b2,
                                                  float* __restrict__ out) {
    int node = blockIdx.x * 8 + (threadIdx.x >> 5);
    int lane = threadIdx.x & 31;
    if (node >= NN) return;
    int e = rs[node];
    const int re = rs[node + 1];
    float4 acc = make_float4(0.f, 0.f, 0.f, 0.f);
    for (; e + 3 < re; e += 4) {
        int2 p0 = csr[e];
        int2 p1 = csr[e + 1];
        int2 p2 = csr[e + 2];
        int2 p3 = csr[e + 3];
        ushort4 v0 = *(const ushort4*)(P + (size_t)p0.x * 128 + lane * 4);
        ushort4 v1 = *(const ushort4*)(P + (size_t)p1.x * 128 + lane * 4);
        ushort4 v2 = *(const ushort4*)(P + (size_t)p2.x * 128 + lane * 4);
        ushort4 v3 = *(const ushort4*)(P + (size_t)p3.x * 128 + lane * 4);
        float w0 = __int_as_float(p0.y), w1 = __int_as_float(p1.y);
        float w2 = __int_as_float(p2.y), w3 = __int_as_float(p3.y);
        acc.x += w0 * bf2f(v0.x) + w1 * bf2f(v1.x) + w2 * bf2f(v2.x) + w3 * bf2f(v3.x);
        acc.y += w0 * bf2f(v0.y) + w1 * bf2f(v1.y) + w2 * bf2f(v2.y) + w3 * bf2f(v3.y);
        acc.z += w0 * bf2f(v0.z) + w1 * bf2f(v1.z) + w2 * bf2f(v2.z) + w3 * bf2f(v3.z);
        acc.w += w0 * bf2f(v0.w) + w1 * bf2f(v1.w) + w2 * bf2f(v2.w) + w3 * bf2f(v3.w);
    }
    for (; e < re; ++e) {
        int2 p0 = csr[e];
        float w0 = __int_as_float(p0.y);
        ushort4 v0 = *(const ushort4*)(P + (size_t)p0.x * 128 + lane * 4);
        acc.x += w0 * bf2f(v0.x); acc.y += w0 * bf2f(v0.y);
        acc.z += w0 * bf2f(v0.z); acc.w += w0 * bf2f(v0.w);
    }
    float4 b = ((const float4*)b2)[lane];
    float4 r;
    r.x = acc.x + b.x; r.y = acc.y + b.y; r.z = acc.z + b.z; r.w = acc.w + b.w;
    ((float4*)(out + (size_t)node * 128))[lane] = r;
}

static inline size_t align_up(size_t x, size_t a) { return (x + a - 1) / a * a; }

extern "C" void kernel_launch(void* const* d_in, const int* in_sizes, int n_in,
                              void* d_out, int out_size, void* d_ws, size_t ws_size,
                              hipStream_t stream) {
    const float* x   = (const float*)d_in[0];
    const int*   esrc = (const int*)d_in[1];
    const int*   edst = (const int*)d_in[2];
    const float* ew  = (const float*)d_in[3];
    const float* W1  = (const float*)d_in[4];
    const float* b1  = (const float*)d_in[5];
    const float* W2  = (const float*)d_in[6];
    const float* b2  = (const float*)d_in[7];
    const float* Fm  = (const float*)d_in[8];
    const float* emb = (const float*)d_in[9];
    float* out = (float*)d_out;

    char* ws = (char*)d_ws;
    size_t off = 0;
    auto alloc = [&](size_t bytes) -> void* {
        void* p = ws + off;
        off = align_up(off + bytes, 256);
        return p;
    };
    unsigned short* B1  = (unsigned short*)alloc((size_t)NN * DD * 2);   // 12.8 MB: h1 row-major, then P
    unsigned short* XS1 = (unsigned short*)alloc((size_t)NN * DD * 2);   // 12.8 MB: swizzled x
    unsigned short* XS2 = (unsigned short*)alloc((size_t)NN * DD * 2);   // 12.8 MB: swizzled emb
    float* Wmat   = (float*)alloc(128 * 128 * 4);
    int*   counts = (int*)alloc((size_t)NN * 4);
    int*   cursor = (int*)alloc((size_t)NN * 4);
    float* ssq    = (float*)alloc(256);
    int*   rs     = (int*)alloc((size_t)(NN + 1) * 4);
    int*   bsum   = (int*)alloc(64 * 4);
    int2*  csr    = (int2*)alloc((size_t)EE * 8);                        // 4.8 MB
    unsigned short* W1th = (unsigned short*)alloc(128 * 128 * 2);
    unsigned short* W1tl = (unsigned short*)alloc(128 * 128 * 2);
    unsigned short* W2th = (unsigned short*)alloc(128 * 128 * 2);
    unsigned short* W2tl = (unsigned short*)alloc(128 * 128 * 2);
    unsigned short* Wmth = (unsigned short*)alloc(128 * 128 * 2);
    unsigned short* Wmtl = (unsigned short*)alloc(128 * 128 * 2);
    if (off > ws_size) return;

    // H (relu output, swizzled bf16, 12.8 MB) lives in d_out's bytes;
    // dead after gemm_pe reads it, before spmm_final writes out.
    unsigned short* H = (unsigned short*)d_out;

    // zero [counts | cursor | ssq]
    size_t zero_bytes = (size_t)((char*)ssq - (char*)counts) + 256;
    hipMemsetAsync(counts, 0, zero_bytes, stream);

    // projection matrix + all weight conversions
    wmat_kernel<<<128, 128, 0, stream>>>(Fm, Wmat, ssq);
    conv_weights<<<192, 256, 0, stream>>>(W1, W2, Wmat, ssq,
                                          W1th, W1tl, W2th, W2tl, Wmth, Wmtl);

    // CSR build (XCD-sliced)
    const int sgrid = NSLICE * FCHUNK;   // 1536
    hist_kernel<<<sgrid, 256, 0, stream>>>(edst, counts);
    scan_blocks<<<NB_SCAN, SCAN_BLK, 0, stream>>>(counts, rs, bsum);
    scan_add<<<NB_SCAN, SCAN_BLK, 0, stream>>>(rs, bsum);
    fill_kernel<<<sgrid, 256, 0, stream>>>(esrc, edst, ew, rs, cursor, csr);

    // x and emb -> swizzled bf16 (one dispatch)
    conv2<<<2 * (NN / 16), 256, 0, stream>>>(x, emb, XS1, XS2);

    const int gemm_grid = (NN + 31) / 32;     // 1563
    const int spmm_grid = (NN + 7) / 8;       // 6250

    // h1 = bf16(x @ W1) -> B1 (row-major)
    gemm_mfma<<<gemm_grid, 256, 0, stream>>>(XS1, W1th, W1tl, B1, NN);
    // h = relu(A @ h1 + b1) -> H swizzled (in d_out bytes)
    spmm_relu<<<spmm_grid, 256, 0, stream>>>(B1, rs, csr, b1, H);
    // P = bf16(h @ W2 + emb @ Wm') -> B1 (row-major; h1 dead)
    gemm_pe<<<gemm_grid, 256, 0, stream>>>(H, XS2, W2th, W2tl, Wmth, Wmtl, B1, NN);
    // out = A @ P + b2
    spmm_final<<<spmm_grid, 256, 0, stream>>>(B1, rs, csr, b2, out);
}

// Round 13
// 168.685 us; speedup vs baseline: 1.1928x; 1.0887x over previous
//
#include <hip/hip_runtime.h>
#include <math.h>

#define NN 50000
#define EE 600000
#define DD 128
#define KAPPA_C 0.95f
#define EPS_C 1e-5f
#define NB_SCAN 49                                  // ceil(50000/1024)
#define NSLICE 8
#define SLICE_N ((NN + NSLICE - 1) / NSLICE)       // 6250
#define FCHUNK 192

typedef short s16x8 __attribute__((ext_vector_type(8)));   // 8 bf16 (4 VGPRs)
typedef float f32x4 __attribute__((ext_vector_type(4)));

__device__ __forceinline__ unsigned short f2bf(float f) {
    union { float f; unsigned int u; } v;
    v.f = f;
    unsigned int r = v.u + 0x7fffu + ((v.u >> 16) & 1u);
    return (unsigned short)(r >> 16);
}
__device__ __forceinline__ float bf2f(unsigned short b) {
    union { unsigned int u; float f; } v;
    v.u = ((unsigned int)b) << 16;
    return v.f;
}
// swizzled layout, element (r, k): (r>>4)*2048 + (k>>3)*128 + (r&15)*8 + (k&7)  [shorts]

// ================ MEGA-PRE: wmat (64 blk) | hist (1536 blk) | conv2 (6250 blk) ================
__global__ __launch_bounds__(256) void mega_pre(const float* __restrict__ Fm,
                                                float* __restrict__ W,
                                                float* __restrict__ ssq,
                                                const int* __restrict__ edst,
                                                int* __restrict__ counts,
                                                const float* __restrict__ x,
                                                const float* __restrict__ emb,
                                                unsigned short* __restrict__ XS1,
                                                unsigned short* __restrict__ XS2) {
    const int b = blockIdx.x;
    if (b < 64) {
        // ---- wmat: W = Fm^T Fm (2 rows/block) + ssq ----
        const int i = (b << 1) + (threadIdx.x >> 7);
        const int j = threadIdx.x & 127;
        float acc = 0.f;
        #pragma unroll 8
        for (int k = 0; k < 128; ++k)
            acc += Fm[k * 128 + i] * Fm[k * 128 + j];
        W[i * 128 + j] = acc;
        __shared__ float red[256];
        red[threadIdx.x] = acc * acc;
        __syncthreads();
        for (int o = 128; o > 0; o >>= 1) {
            if (threadIdx.x < o) red[threadIdx.x] += red[threadIdx.x + o];
            __syncthreads();
        }
        if (threadIdx.x == 0) atomicAdd(ssq, red[0]);
    } else if (b < 64 + NSLICE * FCHUNK) {
        // ---- hist (XCD-sliced) ----
        const int bb = b - 64;
        const int slice = bb & (NSLICE - 1);
        const int lo = slice * SLICE_N;
        const int hi = lo + SLICE_N;
        const int chunk = bb >> 3;
        const int per = (EE + FCHUNK - 1) / FCHUNK;
        const int e0 = chunk * per;
        int e1 = e0 + per; if (e1 > EE) e1 = EE;
        for (int e = e0 + threadIdx.x; e < e1; e += 256) {
            int d = __builtin_nontemporal_load(&edst[e]);
            if (d >= lo && d < hi) atomicAdd(&counts[d], 1);
        }
    } else {
        // ---- conv2: x/emb f32 -> swizzled bf16 ----
        int t = b - (64 + NSLICE * FCHUNK);
        const int half = NN / 16;        // 3125
        const float* in = (t < half) ? x : emb;
        unsigned short* outp = (t < half) ? XS1 : XS2;
        if (t >= half) t -= half;
        const int rl = threadIdx.x >> 4;
        const int kq = threadIdx.x & 15;
        const float* xp = in + (size_t)(t * 16 + rl) * 128 + kq * 8;
        float4 f0 = ((const float4*)xp)[0];
        float4 f1 = ((const float4*)xp)[1];
        union { s16x8 v; unsigned short u[8]; } cv;
        cv.u[0] = f2bf(f0.x); cv.u[1] = f2bf(f0.y); cv.u[2] = f2bf(f0.z); cv.u[3] = f2bf(f0.w);
        cv.u[4] = f2bf(f1.x); cv.u[5] = f2bf(f1.y); cv.u[6] = f2bf(f1.z); cv.u[7] = f2bf(f1.w);
        *(s16x8*)(outp + (size_t)t * 2048 + (size_t)kq * 128 + rl * 8) = cv.v;
    }
}

// ================ MEGA-2: conv_weights (192 blk) | scan_blocks-256 (49 blk) ================
__global__ __launch_bounds__(256) void mega2(const float* __restrict__ W1,
                                             const float* __restrict__ W2,
                                             const float* __restrict__ Wmat,
                                             const float* __restrict__ ssq,
                                             unsigned short* __restrict__ W1th,
                                             unsigned short* __restrict__ W1tl,
                                             unsigned short* __restrict__ W2th,
                                             unsigned short* __restrict__ W2tl,
                                             unsigned short* __restrict__ Wmth,
                                             unsigned short* __restrict__ Wmtl,
                                             const int* __restrict__ counts,
                                             int* __restrict__ rs,
                                             int* __restrict__ bsum) {
    const int b = blockIdx.x;
    if (b < 192) {
        const float* M;
        unsigned short *H, *L;
        float s = 1.0f;
        if (b < 64) { M = W1; H = W1th; L = W1tl; }
        else if (b < 128) { M = W2; H = W2th; L = W2tl; }
        else {
            M = Wmat; H = Wmth; L = Wmtl;
            float n = sqrtf(*ssq);
            s = ((n > 1.0f) ? 1.0f / (n + EPS_C) : 1.0f) * KAPPA_C;
        }
        int id = (b & 63) * 256 + threadIdx.x;   // id = k*128 + c
        float v = M[id] * s;
        int k = id >> 7, c = id & 127;
        size_t o = (size_t)(c >> 4) * 2048 + (size_t)(k >> 3) * 128 + (c & 15) * 8 + (k & 7);
        unsigned short h = f2bf(v);
        H[o] = h;
        L[o] = f2bf(v - bf2f(h));
    } else {
        // scan over 1024 elements with 256 threads (4 per thread)
        const int blk = b - 192;                 // 0..48
        const int tid = threadIdx.x;
        const int gid = blk * 1024 + tid * 4;
        int v0 = (gid + 0 < NN) ? counts[gid + 0] : 0;
        int v1 = (gid + 1 < NN) ? counts[gid + 1] : 0;
        int v2 = (gid + 2 < NN) ? counts[gid + 2] : 0;
        int v3 = (gid + 3 < NN) ? counts[gid + 3] : 0;
        int s0 = v0, s1 = s0 + v1, s2 = s1 + v2, s3 = s2 + v3;
        __shared__ int sd[256];
        sd[tid] = s3;
        __syncthreads();
        for (int o = 1; o < 256; o <<= 1) {
            int t = (tid >= o) ? sd[tid - o] : 0;
            __syncthreads();
            sd[tid] += t;
            __syncthreads();
        }
        int pre = (tid > 0) ? sd[tid - 1] : 0;
        if (gid + 0 < NN) rs[gid + 0] = pre;
        if (gid + 1 < NN) rs[gid + 1] = pre + s0;
        if (gid + 2 < NN) rs[gid + 2] = pre + s1;
        if (gid + 3 < NN) rs[gid + 3] = pre + s2;
        if (tid == 255) bsum[blk] = sd[255];
    }
}

// ================ scan_add (49 blk, 256 thr x 4) ================
__global__ __launch_bounds__(256) void scan_add(int* __restrict__ rs,
                                                const int* __restrict__ bsum) {
    __shared__ int pre;
    if (threadIdx.x == 0) {
        int run = 0;
        for (int i = 0; i < (int)blockIdx.x; ++i) run += bsum[i];
        pre = run;
        if (blockIdx.x == 0) rs[NN] = EE;
    }
    __syncthreads();
    int gid = blockIdx.x * 1024 + threadIdx.x * 4;
    #pragma unroll
    for (int j = 0; j < 4; ++j)
        if (gid + j < NN) rs[gid + j] += pre;
}

// ================ MEGA-3: fill (1536 blk) | gemm_mfma (1563 blk) ================
__global__ __launch_bounds__(256, 4) void mega3(const int* __restrict__ esrc,
                                                const int* __restrict__ edst,
                                                const float* __restrict__ ew,
                                                const int* __restrict__ rs,
                                                int* __restrict__ cursor,
                                                int2* __restrict__ csr,
                                                const unsigned short* __restrict__ Xs,
                                                const unsigned short* __restrict__ Mth,
                                                const unsigned short* __restrict__ Mtl,
                                                unsigned short* __restrict__ outh) {
    const int b = blockIdx.x;
    if (b < NSLICE * FCHUNK) {
        // ---- fill (XCD-sliced) ----
        const int slice = b & (NSLICE - 1);
        const int lo = slice * SLICE_N;
        const int hi = lo + SLICE_N;
        const int chunk = b >> 3;
        const int per = (EE + FCHUNK - 1) / FCHUNK;
        const int e0 = chunk * per;
        int e1 = e0 + per; if (e1 > EE) e1 = EE;
        for (int e = e0 + threadIdx.x; e < e1; e += 256) {
            int d = __builtin_nontemporal_load(&edst[e]);
            if (d >= lo && d < hi) {
                int pos = atomicAdd(&cursor[d], 1);
                csr[rs[d] + pos] = make_int2(__builtin_nontemporal_load(&esrc[e]),
                                             __float_as_int(__builtin_nontemporal_load(&ew[e])));
            }
        }
        return;
    }
    // ---- gemm_mfma: h1 = bf16(x @ W1), swizzled A/B, row-major out ----
    const int gb = b - NSLICE * FCHUNK;
    const int wave = threadIdx.x >> 6;
    const int lane = threadIdx.x & 63;
    const int row0 = gb * 32;
    const int col0 = wave * 32;
    const int lr = lane & 15;
    const int kg = lane >> 4;
    const int lastT = NN / 16 - 1;

    f32x4 acc[2][2];
    #pragma unroll
    for (int m = 0; m < 2; ++m)
        #pragma unroll
        for (int n = 0; n < 2; ++n)
            acc[m][n] = (f32x4){0.f, 0.f, 0.f, 0.f};

    #pragma unroll
    for (int k0 = 0; k0 < 128; k0 += 32) {
        const int kq = (k0 >> 3) + kg;
        s16x8 a[2];
        #pragma unroll
        for (int m = 0; m < 2; ++m) {
            int t = (row0 >> 4) + m;
            if (t > lastT) t = lastT;
            a[m] = *(const s16x8*)(Xs + (size_t)t * 2048 + (size_t)kq * 128 + lr * 8);
        }
        #pragma unroll
        for (int n = 0; n < 2; ++n) {
            const size_t bo = (size_t)((col0 >> 4) + n) * 2048 + (size_t)kq * 128 + lr * 8;
            s16x8 bh = *(const s16x8*)(Mth + bo);
            s16x8 bl = *(const s16x8*)(Mtl + bo);
            #pragma unroll
            for (int m = 0; m < 2; ++m) {
                acc[m][n] = __builtin_amdgcn_mfma_f32_16x16x32_bf16(a[m], bh, acc[m][n], 0, 0, 0);
                acc[m][n] = __builtin_amdgcn_mfma_f32_16x16x32_bf16(a[m], bl, acc[m][n], 0, 0, 0);
            }
        }
    }

    #pragma unroll
    for (int m = 0; m < 2; ++m)
        #pragma unroll
        for (int n = 0; n < 2; ++n)
            #pragma unroll
            for (int j = 0; j < 4; ++j) {
                int r = row0 + m * 16 + kg * 4 + j;
                int c = col0 + n * 16 + lr;
                if (r < NN)
                    outh[(size_t)r * 128 + c] = f2bf(acc[m][n][j]);
            }
}

// ================ dual GEMM: P = bf16( H@W2 + emb@Wm' ), all operands swizzled ================
__global__ __launch_bounds__(256, 4) void gemm_pe(const unsigned short* __restrict__ Hs,
                                                  const unsigned short* __restrict__ Es,
                                                  const unsigned short* __restrict__ W2th,
                                                  const unsigned short* __restrict__ W2tl,
                                                  const unsigned short* __restrict__ Wmth,
                                                  const unsigned short* __restrict__ Wmtl,
                                                  unsigned short* __restrict__ P,
                                                  int nrows) {
    const int wave = threadIdx.x >> 6;
    const int lane = threadIdx.x & 63;
    const int row0 = blockIdx.x * 32;
    const int col0 = wave * 32;
    const int lr = lane & 15;
    const int kg = lane >> 4;
    const int lastT = nrows / 16 - 1;

    f32x4 acc[2][2];
    #pragma unroll
    for (int m = 0; m < 2; ++m)
        #pragma unroll
        for (int n = 0; n < 2; ++n)
            acc[m][n] = (f32x4){0.f, 0.f, 0.f, 0.f};

    #pragma unroll
    for (int k0 = 0; k0 < 128; k0 += 32) {
        const int kq = (k0 >> 3) + kg;
        s16x8 ah[2], ae[2];
        #pragma unroll
        for (int m = 0; m < 2; ++m) {
            int t = (row0 >> 4) + m;
            if (t > lastT) t = lastT;
            const size_t ao = (size_t)t * 2048 + (size_t)kq * 128 + lr * 8;
            ah[m] = *(const s16x8*)(Hs + ao);
            ae[m] = *(const s16x8*)(Es + ao);
        }
        #pragma unroll
        for (int n = 0; n < 2; ++n) {
            const size_t bo = (size_t)((col0 >> 4) + n) * 2048 + (size_t)kq * 128 + lr * 8;
            s16x8 b2h = *(const s16x8*)(W2th + bo);
            s16x8 b2l = *(const s16x8*)(W2tl + bo);
            s16x8 bmh = *(const s16x8*)(Wmth + bo);
            s16x8 bml = *(const s16x8*)(Wmtl + bo);
            #pragma unroll
            for (int m = 0; m < 2; ++m) {
                acc[m][n] = __builtin_amdgcn_mfma_f32_16x16x32_bf16(ah[m], b2h, acc[m][n], 0, 0, 0);
                acc[m][n] = __builtin_amdgcn_mfma_f32_16x16x32_bf16(ah[m], b2l, acc[m][n], 0, 0, 0);
                acc[m][n] = __builtin_amdgcn_mfma_f32_16x16x32_bf16(ae[m], bmh, acc[m][n], 0, 0, 0);
                acc[m][n] = __builtin_amdgcn_mfma_f32_16x16x32_bf16(ae[m], bml, acc[m][n], 0, 0, 0);
            }
        }
    }

    #pragma unroll
    for (int m = 0; m < 2; ++m)
        #pragma unroll
        for (int n = 0; n < 2; ++n)
            #pragma unroll
            for (int j = 0; j < 4; ++j) {
                int r = row0 + m * 16 + kg * 4 + j;
                int c = col0 + n * 16 + lr;
                if (r < nrows)
                    P[(size_t)r * 128 + c] = f2bf(acc[m][n][j]);
            }
}

// edge-gather step macro (32 lanes/node, 8B per lane)
#define GATHER4(P_, E_) \
    int2 p0 = csr[E_], p1 = csr[E_ + 1], p2 = csr[E_ + 2], p3 = csr[E_ + 3]; \
    ushort4 v0 = *(const ushort4*)(P_ + (size_t)p0.x * 128 + lane * 4); \
    ushort4 v1 = *(const ushort4*)(P_ + (size_t)p1.x * 128 + lane * 4); \
    ushort4 v2 = *(const ushort4*)(P_ + (size_t)p2.x * 128 + lane * 4); \
    ushort4 v3 = *(const ushort4*)(P_ + (size_t)p3.x * 128 + lane * 4); \
    float w0 = __int_as_float(p0.y), w1 = __int_as_float(p1.y); \
    float w2 = __int_as_float(p2.y), w3 = __int_as_float(p3.y); \
    acc.x += w0 * bf2f(v0.x) + w1 * bf2f(v1.x) + w2 * bf2f(v2.x) + w3 * bf2f(v3.x); \
    acc.y += w0 * bf2f(v0.y) + w1 * bf2f(v1.y) + w2 * bf2f(v2.y) + w3 * bf2f(v3.y); \
    acc.z += w0 * bf2f(v0.z) + w1 * bf2f(v1.z) + w2 * bf2f(v2.z) + w3 * bf2f(v3.z); \
    acc.w += w0 * bf2f(v0.w) + w1 * bf2f(v1.w) + w2 * bf2f(v2.w) + w3 * bf2f(v3.w);

// ================ SpMM 1: h = relu(A @ h1 + b1); SWIZZLED bf16 out; 8-deep ================
__global__ __launch_bounds__(256) void spmm_relu(const unsigned short* __restrict__ h,
                                                 const int* __restrict__ rs,
                                                 const int2* __restrict__ csr,
                                                 const float* __restrict__ bias,
                                                 unsigned short* __restrict__ Hs) {
    int node = blockIdx.x * 8 + (threadIdx.x >> 5);
    int lane = threadIdx.x & 31;
    if (node >= NN) return;
    int e = rs[node];
    const int re = rs[node + 1];
    float4 acc = make_float4(0.f, 0.f, 0.f, 0.f);
    for (; e + 7 < re; e += 8) {
        { GATHER4(h, e) }
        { GATHER4(h, (e + 4)) }
    }
    for (; e + 3 < re; e += 4) {
        GATHER4(h, e)
    }
    for (; e < re; ++e) {
        int2 p0 = csr[e];
        float w0 = __int_as_float(p0.y);
        ushort4 v0 = *(const ushort4*)(h + (size_t)p0.x * 128 + lane * 4);
        acc.x += w0 * bf2f(v0.x); acc.y += w0 * bf2f(v0.y);
        acc.z += w0 * bf2f(v0.z); acc.w += w0 * bf2f(v0.w);
    }
    float4 b = ((const float4*)bias)[lane];
    acc.x = fmaxf(acc.x + b.x, 0.f); acc.y = fmaxf(acc.y + b.y, 0.f);
    acc.z = fmaxf(acc.z + b.z, 0.f); acc.w = fmaxf(acc.w + b.w, 0.f);
    ushort4 o;
    o.x = f2bf(acc.x); o.y = f2bf(acc.y); o.z = f2bf(acc.z); o.w = f2bf(acc.w);
    size_t so = (size_t)(node >> 4) * 2048 + (size_t)(lane >> 1) * 128
              + (node & 15) * 8 + (lane & 1) * 4;
    *(ushort4*)(Hs + so) = o;
}

// ================ final SpMM: out = A@P + b2 (f32 out); 8-deep ================
__global__ __launch_bounds__(256) void spmm_final(const unsigned short* __restrict__ P,
                                                  const int* __restrict__ rs,
                                                  const int2* __restrict__ csr,
                                                  const float* __restrict__ b2,
                                                  float* __restrict__ out) {
    int node = blockIdx.x * 8 + (threadIdx.x >> 5);
    int lane = threadIdx.x & 31;
    if (node >= NN) return;
    int e = rs[node];
    const int re = rs[node + 1];
    float4 acc = make_float4(0.f, 0.f, 0.f, 0.f);
    for (; e + 7 < re; e += 8) {
        { GATHER4(P, e) }
        { GATHER4(P, (e + 4)) }
    }
    for (; e + 3 < re; e += 4) {
        GATHER4(P, e)
    }
    for (; e < re; ++e) {
        int2 p0 = csr[e];
        float w0 = __int_as_float(p0.y);
        ushort4 v0 = *(const ushort4*)(P + (size_t)p0.x * 128 + lane * 4);
        acc.x += w0 * bf2f(v0.x); acc.y += w0 * bf2f(v0.y);
        acc.z += w0 * bf2f(v0.z); acc.w += w0 * bf2f(v0.w);
    }
    float4 b = ((const float4*)b2)[lane];
    float4 r;
    r.x = acc.x + b.x; r.y = acc.y + b.y; r.z = acc.z + b.z; r.w = acc.w + b.w;
    ((float4*)(out + (size_t)node * 128))[lane] = r;
}

static inline size_t align_up(size_t x, size_t a) { return (x + a - 1) / a * a; }

extern "C" void kernel_launch(void* const* d_in, const int* in_sizes, int n_in,
                              void* d_out, int out_size, void* d_ws, size_t ws_size,
                              hipStream_t stream) {
    const float* x   = (const float*)d_in[0];
    const int*   esrc = (const int*)d_in[1];
    const int*   edst = (const int*)d_in[2];
    const float* ew  = (const float*)d_in[3];
    const float* W1  = (const float*)d_in[4];
    const float* b1  = (const float*)d_in[5];
    const float* W2  = (const float*)d_in[6];
    const float* b2  = (const float*)d_in[7];
    const float* Fm  = (const float*)d_in[8];
    const float* emb = (const float*)d_in[9];
    float* out = (float*)d_out;

    char* ws = (char*)d_ws;
    size_t off = 0;
    auto alloc = [&](size_t bytes) -> void* {
        void* p = ws + off;
        off = align_up(off + bytes, 256);
        return p;
    };
    unsigned short* B1  = (unsigned short*)alloc((size_t)NN * DD * 2);   // 12.8 MB: h1 row-major, then P
    unsigned short* XS1 = (unsigned short*)alloc((size_t)NN * DD * 2);   // 12.8 MB: swizzled x
    unsigned short* XS2 = (unsigned short*)alloc((size_t)NN * DD * 2);   // 12.8 MB: swizzled emb
    float* Wmat   = (float*)alloc(128 * 128 * 4);
    int*   counts = (int*)alloc((size_t)NN * 4);
    int*   cursor = (int*)alloc((size_t)NN * 4);
    float* ssq    = (float*)alloc(256);
    int*   rs     = (int*)alloc((size_t)(NN + 1) * 4);
    int*   bsum   = (int*)alloc(64 * 4);
    int2*  csr    = (int2*)alloc((size_t)EE * 8);                        // 4.8 MB
    unsigned short* W1th = (unsigned short*)alloc(128 * 128 * 2);
    unsigned short* W1tl = (unsigned short*)alloc(128 * 128 * 2);
    unsigned short* W2th = (unsigned short*)alloc(128 * 128 * 2);
    unsigned short* W2tl = (unsigned short*)alloc(128 * 128 * 2);
    unsigned short* Wmth = (unsigned short*)alloc(128 * 128 * 2);
    unsigned short* Wmtl = (unsigned short*)alloc(128 * 128 * 2);
    if (off > ws_size) return;

    // H (relu output, swizzled bf16, 12.8 MB) lives in d_out's bytes;
    // dead after gemm_pe reads it, before spmm_final writes out.
    unsigned short* H = (unsigned short*)d_out;

    // zero [counts | cursor | ssq]
    size_t zero_bytes = (size_t)((char*)ssq - (char*)counts) + 256;
    hipMemsetAsync(counts, 0, zero_bytes, stream);

    const int pre_grid  = 64 + NSLICE * FCHUNK + 2 * (NN / 16);  // 64+1536+6250 = 7850
    const int m2_grid   = 192 + NB_SCAN;                         // 241
    const int m3_grid   = NSLICE * FCHUNK + (NN + 31) / 32;      // 1536+1563 = 3099
    const int gemm_grid = (NN + 31) / 32;                        // 1563
    const int spmm_grid = (NN + 7) / 8;                          // 6250

    // wmat | hist | conv2(x,emb)
    mega_pre<<<pre_grid, 256, 0, stream>>>(Fm, Wmat, ssq, edst, counts, x, emb, XS1, XS2);
    // conv_weights | scan_blocks
    mega2<<<m2_grid, 256, 0, stream>>>(W1, W2, Wmat, ssq,
                                       W1th, W1tl, W2th, W2tl, Wmth, Wmtl,
                                       counts, rs, bsum);
    scan_add<<<NB_SCAN, 256, 0, stream>>>(rs, bsum);
    // fill | gemm_mfma (h1 = bf16(x @ W1) -> B1)
    mega3<<<m3_grid, 256, 0, stream>>>(esrc, edst, ew, rs, cursor, csr,
                                       XS1, W1th, W1tl, B1);
    // h = relu(A @ h1 + b1) -> H swizzled (in d_out bytes)
    spmm_relu<<<spmm_grid, 256, 0, stream>>>(B1, rs, csr, b1, H);
    // P = bf16(h @ W2 + emb @ Wm') -> B1 (row-major; h1 dead)
    gemm_pe<<<gemm_grid, 256, 0, stream>>>(H, XS2, W2th, W2tl, Wmth, Wmtl, B1, NN);
    // out = A @ P + b2
    spmm_final<<<spmm_grid, 256, 0, stream>>>(B1, rs, csr, b2, out);
}

// Round 14
// 163.979 us; speedup vs baseline: 1.2270x; 1.0287x over previous
//
#include <hip/hip_runtime.h>
#include <hip/hip_fp16.h>
#include <math.h>

#define NN 50000
#define EE 600000
#define DD 128
#define KAPPA_C 0.95f
#define EPS_C 1e-5f
#define NB_SCAN 49                                  // ceil(50000/1024)
#define NSLICE 8
#define SLICE_N ((NN + NSLICE - 1) / NSLICE)       // 6250
#define FCHUNK 192

typedef short s16x8 __attribute__((ext_vector_type(8)));   // 8 bf16 (4 VGPRs)
typedef float f32x4 __attribute__((ext_vector_type(4)));

__device__ __forceinline__ unsigned short f2bf(float f) {
    union { float f; unsigned int u; } v;
    v.f = f;
    unsigned int r = v.u + 0x7fffu + ((v.u >> 16) & 1u);
    return (unsigned short)(r >> 16);
}
__device__ __forceinline__ float bf2f(unsigned short b) {
    union { unsigned int u; float f; } v;
    v.u = ((unsigned int)b) << 16;
    return v.f;
}
// 4B CSR entry: [31:16] = f16(weight), [15:0] = u16 src  (NN=50000 < 65536)
__device__ __forceinline__ unsigned int pack_csr(int src, float w) {
    __half h = __float2half_rn(w);
    return ((unsigned int)__half_as_ushort(h) << 16) | (unsigned int)src;
}
__device__ __forceinline__ float csr_w(unsigned int v) {
    return __half2float(__ushort_as_half((unsigned short)(v >> 16)));
}
// swizzled layout, element (r, k): (r>>4)*2048 + (k>>3)*128 + (r&15)*8 + (k&7)  [shorts]

// ================ MEGA-PRE: wmat (64 blk) | hist (1536 blk) | conv2 (6250 blk) ================
__global__ __launch_bounds__(256) void mega_pre(const float* __restrict__ Fm,
                                                float* __restrict__ W,
                                                float* __restrict__ ssq,
                                                const int* __restrict__ edst,
                                                int* __restrict__ counts,
                                                const float* __restrict__ x,
                                                const float* __restrict__ emb,
                                                unsigned short* __restrict__ XS1,
                                                unsigned short* __restrict__ XS2) {
    const int b = blockIdx.x;
    if (b < 64) {
        const int i = (b << 1) + (threadIdx.x >> 7);
        const int j = threadIdx.x & 127;
        float acc = 0.f;
        #pragma unroll 8
        for (int k = 0; k < 128; ++k)
            acc += Fm[k * 128 + i] * Fm[k * 128 + j];
        W[i * 128 + j] = acc;
        __shared__ float red[256];
        red[threadIdx.x] = acc * acc;
        __syncthreads();
        for (int o = 128; o > 0; o >>= 1) {
            if (threadIdx.x < o) red[threadIdx.x] += red[threadIdx.x + o];
            __syncthreads();
        }
        if (threadIdx.x == 0) atomicAdd(ssq, red[0]);
    } else if (b < 64 + NSLICE * FCHUNK) {
        const int bb = b - 64;
        const int slice = bb & (NSLICE - 1);
        const int lo = slice * SLICE_N;
        const int hi = lo + SLICE_N;
        const int chunk = bb >> 3;
        const int per = (EE + FCHUNK - 1) / FCHUNK;
        const int e0 = chunk * per;
        int e1 = e0 + per; if (e1 > EE) e1 = EE;
        for (int e = e0 + threadIdx.x; e < e1; e += 256) {
            int d = __builtin_nontemporal_load(&edst[e]);
            if (d >= lo && d < hi) atomicAdd(&counts[d], 1);
        }
    } else {
        int t = b - (64 + NSLICE * FCHUNK);
        const int half = NN / 16;        // 3125
        const float* in = (t < half) ? x : emb;
        unsigned short* outp = (t < half) ? XS1 : XS2;
        if (t >= half) t -= half;
        const int rl = threadIdx.x >> 4;
        const int kq = threadIdx.x & 15;
        const float* xp = in + (size_t)(t * 16 + rl) * 128 + kq * 8;
        float4 f0 = ((const float4*)xp)[0];
        float4 f1 = ((const float4*)xp)[1];
        union { s16x8 v; unsigned short u[8]; } cv;
        cv.u[0] = f2bf(f0.x); cv.u[1] = f2bf(f0.y); cv.u[2] = f2bf(f0.z); cv.u[3] = f2bf(f0.w);
        cv.u[4] = f2bf(f1.x); cv.u[5] = f2bf(f1.y); cv.u[6] = f2bf(f1.z); cv.u[7] = f2bf(f1.w);
        *(s16x8*)(outp + (size_t)t * 2048 + (size_t)kq * 128 + rl * 8) = cv.v;
    }
}

// ================ MEGA-2: conv_weights (192 blk) | scan_blocks-256 (49 blk) ================
__global__ __launch_bounds__(256) void mega2(const float* __restrict__ W1,
                                             const float* __restrict__ W2,
                                             const float* __restrict__ Wmat,
                                             const float* __restrict__ ssq,
                                             unsigned short* __restrict__ W1th,
                                             unsigned short* __restrict__ W1tl,
                                             unsigned short* __restrict__ W2th,
                                             unsigned short* __restrict__ W2tl,
                                             unsigned short* __restrict__ Wmth,
                                             unsigned short* __restrict__ Wmtl,
                                             const int* __restrict__ counts,
                                             int* __restrict__ rs,
                                             int* __restrict__ bsum) {
    const int b = blockIdx.x;
    if (b < 192) {
        const float* M;
        unsigned short *H, *L;
        float s = 1.0f;
        if (b < 64) { M = W1; H = W1th; L = W1tl; }
        else if (b < 128) { M = W2; H = W2th; L = W2tl; }
        else {
            M = Wmat; H = Wmth; L = Wmtl;
            float n = sqrtf(*ssq);
            s = ((n > 1.0f) ? 1.0f / (n + EPS_C) : 1.0f) * KAPPA_C;
        }
        int id = (b & 63) * 256 + threadIdx.x;   // id = k*128 + c
        float v = M[id] * s;
        int k = id >> 7, c = id & 127;
        size_t o = (size_t)(c >> 4) * 2048 + (size_t)(k >> 3) * 128 + (c & 15) * 8 + (k & 7);
        unsigned short h = f2bf(v);
        H[o] = h;
        L[o] = f2bf(v - bf2f(h));
    } else {
        const int blk = b - 192;                 // 0..48
        const int tid = threadIdx.x;
        const int gid = blk * 1024 + tid * 4;
        int v0 = (gid + 0 < NN) ? counts[gid + 0] : 0;
        int v1 = (gid + 1 < NN) ? counts[gid + 1] : 0;
        int v2 = (gid + 2 < NN) ? counts[gid + 2] : 0;
        int v3 = (gid + 3 < NN) ? counts[gid + 3] : 0;
        int s0 = v0, s1 = s0 + v1, s2 = s1 + v2, s3 = s2 + v3;
        __shared__ int sd[256];
        sd[tid] = s3;
        __syncthreads();
        for (int o = 1; o < 256; o <<= 1) {
            int t = (tid >= o) ? sd[tid - o] : 0;
            __syncthreads();
            sd[tid] += t;
            __syncthreads();
        }
        int pre = (tid > 0) ? sd[tid - 1] : 0;
        if (gid + 0 < NN) rs[gid + 0] = pre;
        if (gid + 1 < NN) rs[gid + 1] = pre + s0;
        if (gid + 2 < NN) rs[gid + 2] = pre + s1;
        if (gid + 3 < NN) rs[gid + 3] = pre + s2;
        if (tid == 255) bsum[blk] = sd[255];
    }
}

// ================ scan_add (49 blk, 256 thr x 4) ================
__global__ __launch_bounds__(256) void scan_add(int* __restrict__ rs,
                                                const int* __restrict__ bsum) {
    __shared__ int pre;
    if (threadIdx.x == 0) {
        int run = 0;
        for (int i = 0; i < (int)blockIdx.x; ++i) run += bsum[i];
        pre = run;
        if (blockIdx.x == 0) rs[NN] = EE;
    }
    __syncthreads();
    int gid = blockIdx.x * 1024 + threadIdx.x * 4;
    #pragma unroll
    for (int j = 0; j < 4; ++j)
        if (gid + j < NN) rs[gid + j] += pre;
}

// ================ MEGA-3: fill (1536 blk, 4B entries) | gemm_mfma (1563 blk) ================
__global__ __launch_bounds__(256, 4) void mega3(const int* __restrict__ esrc,
                                                const int* __restrict__ edst,
                                                const float* __restrict__ ew,
                                                const int* __restrict__ rs,
                                                int* __restrict__ cursor,
                                                unsigned int* __restrict__ csr,
                                                const unsigned short* __restrict__ Xs,
                                                const unsigned short* __restrict__ Mth,
                                                const unsigned short* __restrict__ Mtl,
                                                unsigned short* __restrict__ outh) {
    const int b = blockIdx.x;
    if (b < NSLICE * FCHUNK) {
        const int slice = b & (NSLICE - 1);
        const int lo = slice * SLICE_N;
        const int hi = lo + SLICE_N;
        const int chunk = b >> 3;
        const int per = (EE + FCHUNK - 1) / FCHUNK;
        const int e0 = chunk * per;
        int e1 = e0 + per; if (e1 > EE) e1 = EE;
        for (int e = e0 + threadIdx.x; e < e1; e += 256) {
            int d = __builtin_nontemporal_load(&edst[e]);
            if (d >= lo && d < hi) {
                int pos = atomicAdd(&cursor[d], 1);
                csr[rs[d] + pos] = pack_csr(__builtin_nontemporal_load(&esrc[e]),
                                            __builtin_nontemporal_load(&ew[e]));
            }
        }
        return;
    }
    // ---- gemm_mfma: h1 = bf16(x @ W1), swizzled A/B, row-major out ----
    const int gb = b - NSLICE * FCHUNK;
    const int wave = threadIdx.x >> 6;
    const int lane = threadIdx.x & 63;
    const int row0 = gb * 32;
    const int col0 = wave * 32;
    const int lr = lane & 15;
    const int kg = lane >> 4;
    const int lastT = NN / 16 - 1;

    f32x4 acc[2][2];
    #pragma unroll
    for (int m = 0; m < 2; ++m)
        #pragma unroll
        for (int n = 0; n < 2; ++n)
            acc[m][n] = (f32x4){0.f, 0.f, 0.f, 0.f};

    #pragma unroll
    for (int k0 = 0; k0 < 128; k0 += 32) {
        const int kq = (k0 >> 3) + kg;
        s16x8 a[2];
        #pragma unroll
        for (int m = 0; m < 2; ++m) {
            int t = (row0 >> 4) + m;
            if (t > lastT) t = lastT;
            a[m] = *(const s16x8*)(Xs + (size_t)t * 2048 + (size_t)kq * 128 + lr * 8);
        }
        #pragma unroll
        for (int n = 0; n < 2; ++n) {
            const size_t bo = (size_t)((col0 >> 4) + n) * 2048 + (size_t)kq * 128 + lr * 8;
            s16x8 bh = *(const s16x8*)(Mth + bo);
            s16x8 bl = *(const s16x8*)(Mtl + bo);
            #pragma unroll
            for (int m = 0; m < 2; ++m) {
                acc[m][n] = __builtin_amdgcn_mfma_f32_16x16x32_bf16(a[m], bh, acc[m][n], 0, 0, 0);
                acc[m][n] = __builtin_amdgcn_mfma_f32_16x16x32_bf16(a[m], bl, acc[m][n], 0, 0, 0);
            }
        }
    }

    #pragma unroll
    for (int m = 0; m < 2; ++m)
        #pragma unroll
        for (int n = 0; n < 2; ++n)
            #pragma unroll
            for (int j = 0; j < 4; ++j) {
                int r = row0 + m * 16 + kg * 4 + j;
                int c = col0 + n * 16 + lr;
                if (r < NN)
                    outh[(size_t)r * 128 + c] = f2bf(acc[m][n][j]);
            }
}

// ================ dual GEMM: P = bf16( H@W2 + emb@Wm' ), all operands swizzled ================
__global__ __launch_bounds__(256, 4) void gemm_pe(const unsigned short* __restrict__ Hs,
                                                  const unsigned short* __restrict__ Es,
                                                  const unsigned short* __restrict__ W2th,
                                                  const unsigned short* __restrict__ W2tl,
                                                  const unsigned short* __restrict__ Wmth,
                                                  const unsigned short* __restrict__ Wmtl,
                                                  unsigned short* __restrict__ P,
                                                  int nrows) {
    const int wave = threadIdx.x >> 6;
    const int lane = threadIdx.x & 63;
    const int row0 = blockIdx.x * 32;
    const int col0 = wave * 32;
    const int lr = lane & 15;
    const int kg = lane >> 4;
    const int lastT = nrows / 16 - 1;

    f32x4 acc[2][2];
    #pragma unroll
    for (int m = 0; m < 2; ++m)
        #pragma unroll
        for (int n = 0; n < 2; ++n)
            acc[m][n] = (f32x4){0.f, 0.f, 0.f, 0.f};

    #pragma unroll
    for (int k0 = 0; k0 < 128; k0 += 32) {
        const int kq = (k0 >> 3) + kg;
        s16x8 ah[2], ae[2];
        #pragma unroll
        for (int m = 0; m < 2; ++m) {
            int t = (row0 >> 4) + m;
            if (t > lastT) t = lastT;
            const size_t ao = (size_t)t * 2048 + (size_t)kq * 128 + lr * 8;
            ah[m] = *(const s16x8*)(Hs + ao);
            ae[m] = *(const s16x8*)(Es + ao);
        }
        #pragma unroll
        for (int n = 0; n < 2; ++n) {
            const size_t bo = (size_t)((col0 >> 4) + n) * 2048 + (size_t)kq * 128 + lr * 8;
            s16x8 b2h = *(const s16x8*)(W2th + bo);
            s16x8 b2l = *(const s16x8*)(W2tl + bo);
            s16x8 bmh = *(const s16x8*)(Wmth + bo);
            s16x8 bml = *(const s16x8*)(Wmtl + bo);
            #pragma unroll
            for (int m = 0; m < 2; ++m) {
                acc[m][n] = __builtin_amdgcn_mfma_f32_16x16x32_bf16(ah[m], b2h, acc[m][n], 0, 0, 0);
                acc[m][n] = __builtin_amdgcn_mfma_f32_16x16x32_bf16(ah[m], b2l, acc[m][n], 0, 0, 0);
                acc[m][n] = __builtin_amdgcn_mfma_f32_16x16x32_bf16(ae[m], bmh, acc[m][n], 0, 0, 0);
                acc[m][n] = __builtin_amdgcn_mfma_f32_16x16x32_bf16(ae[m], bml, acc[m][n], 0, 0, 0);
            }
        }
    }

    #pragma unroll
    for (int m = 0; m < 2; ++m)
        #pragma unroll
        for (int n = 0; n < 2; ++n)
            #pragma unroll
            for (int j = 0; j < 4; ++j) {
                int r = row0 + m * 16 + kg * 4 + j;
                int c = col0 + n * 16 + lr;
                if (r < nrows)
                    P[(size_t)r * 128 + c] = f2bf(acc[m][n][j]);
            }
}

// edge-gather step macro (32 lanes/node, 4B CSR entries)
#define GATHER4(P_, E_) \
    unsigned int p0 = csr[E_], p1 = csr[E_ + 1], p2 = csr[E_ + 2], p3 = csr[E_ + 3]; \
    ushort4 v0 = *(const ushort4*)(P_ + (size_t)(p0 & 0xffffu) * 128 + lane * 4); \
    ushort4 v1 = *(const ushort4*)(P_ + (size_t)(p1 & 0xffffu) * 128 + lane * 4); \
    ushort4 v2 = *(const ushort4*)(P_ + (size_t)(p2 & 0xffffu) * 128 + lane * 4); \
    ushort4 v3 = *(const ushort4*)(P_ + (size_t)(p3 & 0xffffu) * 128 + lane * 4); \
    float w0 = csr_w(p0), w1 = csr_w(p1); \
    float w2 = csr_w(p2), w3 = csr_w(p3); \
    acc.x += w0 * bf2f(v0.x) + w1 * bf2f(v1.x) + w2 * bf2f(v2.x) + w3 * bf2f(v3.x); \
    acc.y += w0 * bf2f(v0.y) + w1 * bf2f(v1.y) + w2 * bf2f(v2.y) + w3 * bf2f(v3.y); \
    acc.z += w0 * bf2f(v0.z) + w1 * bf2f(v1.z) + w2 * bf2f(v2.z) + w3 * bf2f(v3.z); \
    acc.w += w0 * bf2f(v0.w) + w1 * bf2f(v1.w) + w2 * bf2f(v2.w) + w3 * bf2f(v3.w);

// ================ SpMM 1: h = relu(A @ h1 + b1); SWIZZLED bf16 out; 8-deep ================
__global__ __launch_bounds__(256) void spmm_relu(const unsigned short* __restrict__ h,
                                                 const int* __restrict__ rs,
                                                 const unsigned int* __restrict__ csr,
                                                 const float* __restrict__ bias,
                                                 unsigned short* __restrict__ Hs) {
    int node = blockIdx.x * 8 + (threadIdx.x >> 5);
    int lane = threadIdx.x & 31;
    if (node >= NN) return;
    int e = rs[node];
    const int re = rs[node + 1];
    float4 acc = make_float4(0.f, 0.f, 0.f, 0.f);
    for (; e + 7 < re; e += 8) {
        { GATHER4(h, e) }
        { GATHER4(h, (e + 4)) }
    }
    for (; e + 3 < re; e += 4) {
        GATHER4(h, e)
    }
    for (; e < re; ++e) {
        unsigned int p0 = csr[e];
        float w0 = csr_w(p0);
        ushort4 v0 = *(const ushort4*)(h + (size_t)(p0 & 0xffffu) * 128 + lane * 4);
        acc.x += w0 * bf2f(v0.x); acc.y += w0 * bf2f(v0.y);
        acc.z += w0 * bf2f(v0.z); acc.w += w0 * bf2f(v0.w);
    }
    float4 b = ((const float4*)bias)[lane];
    acc.x = fmaxf(acc.x + b.x, 0.f); acc.y = fmaxf(acc.y + b.y, 0.f);
    acc.z = fmaxf(acc.z + b.z, 0.f); acc.w = fmaxf(acc.w + b.w, 0.f);
    ushort4 o;
    o.x = f2bf(acc.x); o.y = f2bf(acc.y); o.z = f2bf(acc.z); o.w = f2bf(acc.w);
    size_t so = (size_t)(node >> 4) * 2048 + (size_t)(lane >> 1) * 128
              + (node & 15) * 8 + (lane & 1) * 4;
    *(ushort4*)(Hs + so) = o;
}

// ================ final SpMM: out = A@P + b2 (f32 out); 8-deep ================
__global__ __launch_bounds__(256) void spmm_final(const unsigned short* __restrict__ P,
                                                  const int* __restrict__ rs,
                                                  const unsigned int* __restrict__ csr,
                                                  const float* __restrict__ b2,
                                                  float* __restrict__ out) {
    int node = blockIdx.x * 8 + (threadIdx.x >> 5);
    int lane = threadIdx.x & 31;
    if (node >= NN) return;
    int e = rs[node];
    const int re = rs[node + 1];
    float4 acc = make_float4(0.f, 0.f, 0.f, 0.f);
    for (; e + 7 < re; e += 8) {
        { GATHER4(P, e) }
        { GATHER4(P, (e + 4)) }
    }
    for (; e + 3 < re; e += 4) {
        GATHER4(P, e)
    }
    for (; e < re; ++e) {
        unsigned int p0 = csr[e];
        float w0 = csr_w(p0);
        ushort4 v0 = *(const ushort4*)(P + (size_t)(p0 & 0xffffu) * 128 + lane * 4);
        acc.x += w0 * bf2f(v0.x); acc.y += w0 * bf2f(v0.y);
        acc.z += w0 * bf2f(v0.z); acc.w += w0 * bf2f(v0.w);
    }
    float4 b = ((const float4*)b2)[lane];
    float4 r;
    r.x = acc.x + b.x; r.y = acc.y + b.y; r.z = acc.z + b.z; r.w = acc.w + b.w;
    ((float4*)(out + (size_t)node * 128))[lane] = r;
}

static inline size_t align_up(size_t x, size_t a) { return (x + a - 1) / a * a; }

extern "C" void kernel_launch(void* const* d_in, const int* in_sizes, int n_in,
                              void* d_out, int out_size, void* d_ws, size_t ws_size,
                              hipStream_t stream) {
    const float* x   = (const float*)d_in[0];
    const int*   esrc = (const int*)d_in[1];
    const int*   edst = (const int*)d_in[2];
    const float* ew  = (const float*)d_in[3];
    const float* W1  = (const float*)d_in[4];
    const float* b1  = (const float*)d_in[5];
    const float* W2  = (const float*)d_in[6];
    const float* b2  = (const float*)d_in[7];
    const float* Fm  = (const float*)d_in[8];
    const float* emb = (const float*)d_in[9];
    float* out = (float*)d_out;

    char* ws = (char*)d_ws;
    size_t off = 0;
    auto alloc = [&](size_t bytes) -> void* {
        void* p = ws + off;
        off = align_up(off + bytes, 256);
        return p;
    };
    unsigned short* B1  = (unsigned short*)alloc((size_t)NN * DD * 2);   // 12.8 MB: h1 row-major, then P
    unsigned short* XS1 = (unsigned short*)alloc((size_t)NN * DD * 2);   // 12.8 MB: swizzled x
    unsigned short* XS2 = (unsigned short*)alloc((size_t)NN * DD * 2);   // 12.8 MB: swizzled emb
    float* Wmat   = (float*)alloc(128 * 128 * 4);
    int*   counts = (int*)alloc((size_t)NN * 4);
    int*   cursor = (int*)alloc((size_t)NN * 4);
    float* ssq    = (float*)alloc(256);
    int*   rs     = (int*)alloc((size_t)(NN + 1) * 4);
    int*   bsum   = (int*)alloc(64 * 4);
    unsigned int* csr = (unsigned int*)alloc((size_t)EE * 4);            // 2.4 MB packed {f16 w | u16 src}
    unsigned short* W1th = (unsigned short*)alloc(128 * 128 * 2);
    unsigned short* W1tl = (unsigned short*)alloc(128 * 128 * 2);
    unsigned short* W2th = (unsigned short*)alloc(128 * 128 * 2);
    unsigned short* W2tl = (unsigned short*)alloc(128 * 128 * 2);
    unsigned short* Wmth = (unsigned short*)alloc(128 * 128 * 2);
    unsigned short* Wmtl = (unsigned short*)alloc(128 * 128 * 2);
    if (off > ws_size) return;

    // H (relu output, swizzled bf16, 12.8 MB) lives in d_out's bytes;
    // dead after gemm_pe reads it, before spmm_final writes out.
    unsigned short* H = (unsigned short*)d_out;

    // zero [counts | cursor | ssq]
    size_t zero_bytes = (size_t)((char*)ssq - (char*)counts) + 256;
    hipMemsetAsync(counts, 0, zero_bytes, stream);

    const int pre_grid  = 64 + NSLICE * FCHUNK + 2 * (NN / 16);  // 7850
    const int m2_grid   = 192 + NB_SCAN;                         // 241
    const int m3_grid   = NSLICE * FCHUNK + (NN + 31) / 32;      // 3099
    const int gemm_grid = (NN + 31) / 32;                        // 1563
    const int spmm_grid = (NN + 7) / 8;                          // 6250

    // wmat | hist | conv2(x,emb)
    mega_pre<<<pre_grid, 256, 0, stream>>>(Fm, Wmat, ssq, edst, counts, x, emb, XS1, XS2);
    // conv_weights | scan_blocks
    mega2<<<m2_grid, 256, 0, stream>>>(W1, W2, Wmat, ssq,
                                       W1th, W1tl, W2th, W2tl, Wmth, Wmtl,
                                       counts, rs, bsum);
    scan_add<<<NB_SCAN, 256, 0, stream>>>(rs, bsum);
    // fill | gemm_mfma (h1 = bf16(x @ W1) -> B1)
    mega3<<<m3_grid, 256, 0, stream>>>(esrc, edst, ew, rs, cursor, csr,
                                       XS1, W1th, W1tl, B1);
    // h = relu(A @ h1 + b1) -> H swizzled (in d_out bytes)
    spmm_relu<<<spmm_grid, 256, 0, stream>>>(B1, rs, csr, b1, H);
    // P = bf16(h @ W2 + emb @ Wm') -> B1 (row-major; h1 dead)
    gemm_pe<<<gemm_grid, 256, 0, stream>>>(H, XS2, W2th, W2tl, Wmth, Wmtl, B1, NN);
    // out = A @ P + b2
    spmm_final<<<spmm_grid, 256, 0, stream>>>(B1, rs, csr, b2, out);
}

// Round 15
// 163.843 us; speedup vs baseline: 1.2280x; 1.0008x over previous
//
#include <hip/hip_runtime.h>
#include <hip/hip_fp16.h>
#include <math.h>

#define NN 50000
#define EE 600000
#define DD 128
#define KAPPA_C 0.95f
#define EPS_C 1e-5f
#define NB_SCAN 49                                  // ceil(50000/1024)
#define NSLICE 8
#define SLICE_N ((NN + NSLICE - 1) / NSLICE)       // 6250
#define FCHUNK 192

typedef short s16x8 __attribute__((ext_vector_type(8)));   // 8 bf16 (4 VGPRs)
typedef float f32x4 __attribute__((ext_vector_type(4)));

__device__ __forceinline__ unsigned short f2bf(float f) {
    union { float f; unsigned int u; } v;
    v.f = f;
    unsigned int r = v.u + 0x7fffu + ((v.u >> 16) & 1u);
    return (unsigned short)(r >> 16);
}
__device__ __forceinline__ float bf2f(unsigned short b) {
    union { unsigned int u; float f; } v;
    v.u = ((unsigned int)b) << 16;
    return v.f;
}
// 4B CSR entry: [31:16] = f16(weight), [15:0] = u16 src  (NN=50000 < 65536)
__device__ __forceinline__ unsigned int pack_csr(int src, float w) {
    __half h = __float2half_rn(w);
    return ((unsigned int)__half_as_ushort(h) << 16) | (unsigned int)src;
}
__device__ __forceinline__ float csr_w(unsigned int v) {
    return __half2float(__ushort_as_half((unsigned short)(v >> 16)));
}
// swizzled layout, element (r, k): (r>>4)*2048 + (k>>3)*128 + (r&15)*8 + (k&7)  [shorts]

// ================ MEGA-PRE: wmat (64 blk) | hist (1536 blk) | conv2 (6250 blk) ================
__global__ __launch_bounds__(256) void mega_pre(const float* __restrict__ Fm,
                                                float* __restrict__ W,
                                                float* __restrict__ ssq,
                                                const int* __restrict__ edst,
                                                int* __restrict__ counts,
                                                const float* __restrict__ x,
                                                const float* __restrict__ emb,
                                                unsigned short* __restrict__ XS1,
                                                unsigned short* __restrict__ XS2) {
    const int b = blockIdx.x;
    if (b < 64) {
        const int i = (b << 1) + (threadIdx.x >> 7);
        const int j = threadIdx.x & 127;
        float acc = 0.f;
        #pragma unroll 8
        for (int k = 0; k < 128; ++k)
            acc += Fm[k * 128 + i] * Fm[k * 128 + j];
        W[i * 128 + j] = acc;
        __shared__ float red[256];
        red[threadIdx.x] = acc * acc;
        __syncthreads();
        for (int o = 128; o > 0; o >>= 1) {
            if (threadIdx.x < o) red[threadIdx.x] += red[threadIdx.x + o];
            __syncthreads();
        }
        if (threadIdx.x == 0) atomicAdd(ssq, red[0]);
    } else if (b < 64 + NSLICE * FCHUNK) {
        const int bb = b - 64;
        const int slice = bb & (NSLICE - 1);
        const int lo = slice * SLICE_N;
        const int hi = lo + SLICE_N;
        const int chunk = bb >> 3;
        const int per = (EE + FCHUNK - 1) / FCHUNK;
        const int e0 = chunk * per;
        int e1 = e0 + per; if (e1 > EE) e1 = EE;
        for (int e = e0 + threadIdx.x; e < e1; e += 256) {
            int d = __builtin_nontemporal_load(&edst[e]);
            if (d >= lo && d < hi) atomicAdd(&counts[d], 1);
        }
    } else {
        int t = b - (64 + NSLICE * FCHUNK);
        const int half = NN / 16;        // 3125
        const float* in = (t < half) ? x : emb;
        unsigned short* outp = (t < half) ? XS1 : XS2;
        if (t >= half) t -= half;
        const int rl = threadIdx.x >> 4;
        const int kq = threadIdx.x & 15;
        const float* xp = in + (size_t)(t * 16 + rl) * 128 + kq * 8;
        float4 f0 = ((const float4*)xp)[0];
        float4 f1 = ((const float4*)xp)[1];
        union { s16x8 v; unsigned short u[8]; } cv;
        cv.u[0] = f2bf(f0.x); cv.u[1] = f2bf(f0.y); cv.u[2] = f2bf(f0.z); cv.u[3] = f2bf(f0.w);
        cv.u[4] = f2bf(f1.x); cv.u[5] = f2bf(f1.y); cv.u[6] = f2bf(f1.z); cv.u[7] = f2bf(f1.w);
        *(s16x8*)(outp + (size_t)t * 2048 + (size_t)kq * 128 + rl * 8) = cv.v;
    }
}

// ================ MEGA-2: conv_weights (192 blk) | scan_blocks-256 (49 blk) ================
__global__ __launch_bounds__(256) void mega2(const float* __restrict__ W1,
                                             const float* __restrict__ W2,
                                             const float* __restrict__ Wmat,
                                             const float* __restrict__ ssq,
                                             unsigned short* __restrict__ W1th,
                                             unsigned short* __restrict__ W1tl,
                                             unsigned short* __restrict__ W2th,
                                             unsigned short* __restrict__ W2tl,
                                             unsigned short* __restrict__ Wmth,
                                             unsigned short* __restrict__ Wmtl,
                                             const int* __restrict__ counts,
                                             int* __restrict__ rs,
                                             int* __restrict__ bsum) {
    const int b = blockIdx.x;
    if (b < 192) {
        const float* M;
        unsigned short *H, *L;
        float s = 1.0f;
        if (b < 64) { M = W1; H = W1th; L = W1tl; }
        else if (b < 128) { M = W2; H = W2th; L = W2tl; }
        else {
            M = Wmat; H = Wmth; L = Wmtl;
            float n = sqrtf(*ssq);
            s = ((n > 1.0f) ? 1.0f / (n + EPS_C) : 1.0f) * KAPPA_C;
        }
        int id = (b & 63) * 256 + threadIdx.x;   // id = k*128 + c
        float v = M[id] * s;
        int k = id >> 7, c = id & 127;
        size_t o = (size_t)(c >> 4) * 2048 + (size_t)(k >> 3) * 128 + (c & 15) * 8 + (k & 7);
        unsigned short h = f2bf(v);
        H[o] = h;
        L[o] = f2bf(v - bf2f(h));
    } else {
        const int blk = b - 192;                 // 0..48
        const int tid = threadIdx.x;
        const int gid = blk * 1024 + tid * 4;
        int v0 = (gid + 0 < NN) ? counts[gid + 0] : 0;
        int v1 = (gid + 1 < NN) ? counts[gid + 1] : 0;
        int v2 = (gid + 2 < NN) ? counts[gid + 2] : 0;
        int v3 = (gid + 3 < NN) ? counts[gid + 3] : 0;
        int s0 = v0, s1 = s0 + v1, s2 = s1 + v2, s3 = s2 + v3;
        __shared__ int sd[256];
        sd[tid] = s3;
        __syncthreads();
        for (int o = 1; o < 256; o <<= 1) {
            int t = (tid >= o) ? sd[tid - o] : 0;
            __syncthreads();
            sd[tid] += t;
            __syncthreads();
        }
        int pre = (tid > 0) ? sd[tid - 1] : 0;
        if (gid + 0 < NN) rs[gid + 0] = pre;
        if (gid + 1 < NN) rs[gid + 1] = pre + s0;
        if (gid + 2 < NN) rs[gid + 2] = pre + s1;
        if (gid + 3 < NN) rs[gid + 3] = pre + s2;
        if (tid == 255) bsum[blk] = sd[255];
    }
}

// ================ scan_add (49 blk, 256 thr x 4) ================
__global__ __launch_bounds__(256) void scan_add(int* __restrict__ rs,
                                                const int* __restrict__ bsum) {
    __shared__ int pre;
    if (threadIdx.x == 0) {
        int run = 0;
        for (int i = 0; i < (int)blockIdx.x; ++i) run += bsum[i];
        pre = run;
        if (blockIdx.x == 0) rs[NN] = EE;
    }
    __syncthreads();
    int gid = blockIdx.x * 1024 + threadIdx.x * 4;
    #pragma unroll
    for (int j = 0; j < 4; ++j)
        if (gid + j < NN) rs[gid + j] += pre;
}

// ================ fill (1536 blk, 4B entries) — standalone, L2-resident scatter ================
__global__ __launch_bounds__(256) void fill_kernel(const int* __restrict__ esrc,
                                                   const int* __restrict__ edst,
                                                   const float* __restrict__ ew,
                                                   const int* __restrict__ rs,
                                                   int* __restrict__ cursor,
                                                   unsigned int* __restrict__ csr) {
    const int b = blockIdx.x;
    const int slice = b & (NSLICE - 1);
    const int lo = slice * SLICE_N;
    const int hi = lo + SLICE_N;
    const int chunk = b >> 3;
    const int per = (EE + FCHUNK - 1) / FCHUNK;
    const int e0 = chunk * per;
    int e1 = e0 + per; if (e1 > EE) e1 = EE;
    for (int e = e0 + threadIdx.x; e < e1; e += 256) {
        int d = __builtin_nontemporal_load(&edst[e]);
        if (d >= lo && d < hi) {
            int pos = atomicAdd(&cursor[d], 1);
            csr[rs[d] + pos] = pack_csr(__builtin_nontemporal_load(&esrc[e]),
                                        __builtin_nontemporal_load(&ew[e]));
        }
    }
}

// ================ gemm_mfma (1563 blk): h1 = bf16(x @ W1), standalone ================
__global__ __launch_bounds__(256, 4) void gemm_mfma(const unsigned short* __restrict__ Xs,
                                                    const unsigned short* __restrict__ Mth,
                                                    const unsigned short* __restrict__ Mtl,
                                                    unsigned short* __restrict__ outh) {
    const int wave = threadIdx.x >> 6;
    const int lane = threadIdx.x & 63;
    const int row0 = blockIdx.x * 32;
    const int col0 = wave * 32;
    const int lr = lane & 15;
    const int kg = lane >> 4;
    const int lastT = NN / 16 - 1;

    f32x4 acc[2][2];
    #pragma unroll
    for (int m = 0; m < 2; ++m)
        #pragma unroll
        for (int n = 0; n < 2; ++n)
            acc[m][n] = (f32x4){0.f, 0.f, 0.f, 0.f};

    #pragma unroll
    for (int k0 = 0; k0 < 128; k0 += 32) {
        const int kq = (k0 >> 3) + kg;
        s16x8 a[2];
        #pragma unroll
        for (int m = 0; m < 2; ++m) {
            int t = (row0 >> 4) + m;
            if (t > lastT) t = lastT;
            a[m] = *(const s16x8*)(Xs + (size_t)t * 2048 + (size_t)kq * 128 + lr * 8);
        }
        #pragma unroll
        for (int n = 0; n < 2; ++n) {
            const size_t bo = (size_t)((col0 >> 4) + n) * 2048 + (size_t)kq * 128 + lr * 8;
            s16x8 bh = *(const s16x8*)(Mth + bo);
            s16x8 bl = *(const s16x8*)(Mtl + bo);
            #pragma unroll
            for (int m = 0; m < 2; ++m) {
                acc[m][n] = __builtin_amdgcn_mfma_f32_16x16x32_bf16(a[m], bh, acc[m][n], 0, 0, 0);
                acc[m][n] = __builtin_amdgcn_mfma_f32_16x16x32_bf16(a[m], bl, acc[m][n], 0, 0, 0);
            }
        }
    }

    #pragma unroll
    for (int m = 0; m < 2; ++m)
        #pragma unroll
        for (int n = 0; n < 2; ++n)
            #pragma unroll
            for (int j = 0; j < 4; ++j) {
                int r = row0 + m * 16 + kg * 4 + j;
                int c = col0 + n * 16 + lr;
                if (r < NN)
                    outh[(size_t)r * 128 + c] = f2bf(acc[m][n][j]);
            }
}

// ================ dual GEMM: P = bf16( H@W2 + emb@Wm' ), all operands swizzled ================
__global__ __launch_bounds__(256, 4) void gemm_pe(const unsigned short* __restrict__ Hs,
                                                  const unsigned short* __restrict__ Es,
                                                  const unsigned short* __restrict__ W2th,
                                                  const unsigned short* __restrict__ W2tl,
                                                  const unsigned short* __restrict__ Wmth,
                                                  const unsigned short* __restrict__ Wmtl,
                                                  unsigned short* __restrict__ P,
                                                  int nrows) {
    const int wave = threadIdx.x >> 6;
    const int lane = threadIdx.x & 63;
    const int row0 = blockIdx.x * 32;
    const int col0 = wave * 32;
    const int lr = lane & 15;
    const int kg = lane >> 4;
    const int lastT = nrows / 16 - 1;

    f32x4 acc[2][2];
    #pragma unroll
    for (int m = 0; m < 2; ++m)
        #pragma unroll
        for (int n = 0; n < 2; ++n)
            acc[m][n] = (f32x4){0.f, 0.f, 0.f, 0.f};

    #pragma unroll
    for (int k0 = 0; k0 < 128; k0 += 32) {
        const int kq = (k0 >> 3) + kg;
        s16x8 ah[2], ae[2];
        #pragma unroll
        for (int m = 0; m < 2; ++m) {
            int t = (row0 >> 4) + m;
            if (t > lastT) t = lastT;
            const size_t ao = (size_t)t * 2048 + (size_t)kq * 128 + lr * 8;
            ah[m] = *(const s16x8*)(Hs + ao);
            ae[m] = *(const s16x8*)(Es + ao);
        }
        #pragma unroll
        for (int n = 0; n < 2; ++n) {
            const size_t bo = (size_t)((col0 >> 4) + n) * 2048 + (size_t)kq * 128 + lr * 8;
            s16x8 b2h = *(const s16x8*)(W2th + bo);
            s16x8 b2l = *(const s16x8*)(W2tl + bo);
            s16x8 bmh = *(const s16x8*)(Wmth + bo);
            s16x8 bml = *(const s16x8*)(Wmtl + bo);
            #pragma unroll
            for (int m = 0; m < 2; ++m) {
                acc[m][n] = __builtin_amdgcn_mfma_f32_16x16x32_bf16(ah[m], b2h, acc[m][n], 0, 0, 0);
                acc[m][n] = __builtin_amdgcn_mfma_f32_16x16x32_bf16(ah[m], b2l, acc[m][n], 0, 0, 0);
                acc[m][n] = __builtin_amdgcn_mfma_f32_16x16x32_bf16(ae[m], bmh, acc[m][n], 0, 0, 0);
                acc[m][n] = __builtin_amdgcn_mfma_f32_16x16x32_bf16(ae[m], bml, acc[m][n], 0, 0, 0);
            }
        }
    }

    #pragma unroll
    for (int m = 0; m < 2; ++m)
        #pragma unroll
        for (int n = 0; n < 2; ++n)
            #pragma unroll
            for (int j = 0; j < 4; ++j) {
                int r = row0 + m * 16 + kg * 4 + j;
                int c = col0 + n * 16 + lr;
                if (r < nrows)
                    P[(size_t)r * 128 + c] = f2bf(acc[m][n][j]);
            }
}

// edge-gather step macro (32 lanes/node, 4B CSR entries)
#define GATHER4(P_, E_) \
    unsigned int p0 = csr[E_], p1 = csr[E_ + 1], p2 = csr[E_ + 2], p3 = csr[E_ + 3]; \
    ushort4 v0 = *(const ushort4*)(P_ + (size_t)(p0 & 0xffffu) * 128 + lane * 4); \
    ushort4 v1 = *(const ushort4*)(P_ + (size_t)(p1 & 0xffffu) * 128 + lane * 4); \
    ushort4 v2 = *(const ushort4*)(P_ + (size_t)(p2 & 0xffffu) * 128 + lane * 4); \
    ushort4 v3 = *(const ushort4*)(P_ + (size_t)(p3 & 0xffffu) * 128 + lane * 4); \
    float w0 = csr_w(p0), w1 = csr_w(p1); \
    float w2 = csr_w(p2), w3 = csr_w(p3); \
    acc.x += w0 * bf2f(v0.x) + w1 * bf2f(v1.x) + w2 * bf2f(v2.x) + w3 * bf2f(v3.x); \
    acc.y += w0 * bf2f(v0.y) + w1 * bf2f(v1.y) + w2 * bf2f(v2.y) + w3 * bf2f(v3.y); \
    acc.z += w0 * bf2f(v0.z) + w1 * bf2f(v1.z) + w2 * bf2f(v2.z) + w3 * bf2f(v3.z); \
    acc.w += w0 * bf2f(v0.w) + w1 * bf2f(v1.w) + w2 * bf2f(v2.w) + w3 * bf2f(v3.w);

// ================ SpMM 1: h = relu(A @ h1 + b1); SWIZZLED bf16 out; 8-deep ================
__global__ __launch_bounds__(256) void spmm_relu(const unsigned short* __restrict__ h,
                                                 const int* __restrict__ rs,
                                                 const unsigned int* __restrict__ csr,
                                                 const float* __restrict__ bias,
                                                 unsigned short* __restrict__ Hs) {
    int node = blockIdx.x * 8 + (threadIdx.x >> 5);
    int lane = threadIdx.x & 31;
    if (node >= NN) return;
    int e = rs[node];
    const int re = rs[node + 1];
    float4 acc = make_float4(0.f, 0.f, 0.f, 0.f);
    for (; e + 7 < re; e += 8) {
        { GATHER4(h, e) }
        { GATHER4(h, (e + 4)) }
    }
    for (; e + 3 < re; e += 4) {
        GATHER4(h, e)
    }
    for (; e < re; ++e) {
        unsigned int p0 = csr[e];
        float w0 = csr_w(p0);
        ushort4 v0 = *(const ushort4*)(h + (size_t)(p0 & 0xffffu) * 128 + lane * 4);
        acc.x += w0 * bf2f(v0.x); acc.y += w0 * bf2f(v0.y);
        acc.z += w0 * bf2f(v0.z); acc.w += w0 * bf2f(v0.w);
    }
    float4 b = ((const float4*)bias)[lane];
    acc.x = fmaxf(acc.x + b.x, 0.f); acc.y = fmaxf(acc.y + b.y, 0.f);
    acc.z = fmaxf(acc.z + b.z, 0.f); acc.w = fmaxf(acc.w + b.w, 0.f);
    ushort4 o;
    o.x = f2bf(acc.x); o.y = f2bf(acc.y); o.z = f2bf(acc.z); o.w = f2bf(acc.w);
    size_t so = (size_t)(node >> 4) * 2048 + (size_t)(lane >> 1) * 128
              + (node & 15) * 8 + (lane & 1) * 4;
    *(ushort4*)(Hs + so) = o;
}

// ================ final SpMM: out = A@P + b2 (f32 out); 8-deep ================
__global__ __launch_bounds__(256) void spmm_final(const unsigned short* __restrict__ P,
                                                  const int* __restrict__ rs,
                                                  const unsigned int* __restrict__ csr,
                                                  const float* __restrict__ b2,
                                                  float* __restrict__ out) {
    int node = blockIdx.x * 8 + (threadIdx.x >> 5);
    int lane = threadIdx.x & 31;
    if (node >= NN) return;
    int e = rs[node];
    const int re = rs[node + 1];
    float4 acc = make_float4(0.f, 0.f, 0.f, 0.f);
    for (; e + 7 < re; e += 8) {
        { GATHER4(P, e) }
        { GATHER4(P, (e + 4)) }
    }
    for (; e + 3 < re; e += 4) {
        GATHER4(P, e)
    }
    for (; e < re; ++e) {
        unsigned int p0 = csr[e];
        float w0 = csr_w(p0);
        ushort4 v0 = *(const ushort4*)(P + (size_t)(p0 & 0xffffu) * 128 + lane * 4);
        acc.x += w0 * bf2f(v0.x); acc.y += w0 * bf2f(v0.y);
        acc.z += w0 * bf2f(v0.z); acc.w += w0 * bf2f(v0.w);
    }
    float4 b = ((const float4*)b2)[lane];
    float4 r;
    r.x = acc.x + b.x; r.y = acc.y + b.y; r.z = acc.z + b.z; r.w = acc.w + b.w;
    ((float4*)(out + (size_t)node * 128))[lane] = r;
}

static inline size_t align_up(size_t x, size_t a) { return (x + a - 1) / a * a; }

extern "C" void kernel_launch(void* const* d_in, const int* in_sizes, int n_in,
                              void* d_out, int out_size, void* d_ws, size_t ws_size,
                              hipStream_t stream) {
    const float* x   = (const float*)d_in[0];
    const int*   esrc = (const int*)d_in[1];
    const int*   edst = (const int*)d_in[2];
    const float* ew  = (const float*)d_in[3];
    const float* W1  = (const float*)d_in[4];
    const float* b1  = (const float*)d_in[5];
    const float* W2  = (const float*)d_in[6];
    const float* b2  = (const float*)d_in[7];
    const float* Fm  = (const float*)d_in[8];
    const float* emb = (const float*)d_in[9];
    float* out = (float*)d_out;

    char* ws = (char*)d_ws;
    size_t off = 0;
    auto alloc = [&](size_t bytes) -> void* {
        void* p = ws + off;
        off = align_up(off + bytes, 256);
        return p;
    };
    unsigned short* B1  = (unsigned short*)alloc((size_t)NN * DD * 2);   // 12.8 MB: h1 row-major, then P
    unsigned short* XS1 = (unsigned short*)alloc((size_t)NN * DD * 2);   // 12.8 MB: swizzled x
    unsigned short* XS2 = (unsigned short*)alloc((size_t)NN * DD * 2);   // 12.8 MB: swizzled emb
    float* Wmat   = (float*)alloc(128 * 128 * 4);
    int*   counts = (int*)alloc((size_t)NN * 4);
    int*   cursor = (int*)alloc((size_t)NN * 4);
    float* ssq    = (float*)alloc(256);
    int*   rs     = (int*)alloc((size_t)(NN + 1) * 4);
    int*   bsum   = (int*)alloc(64 * 4);
    unsigned int* csr = (unsigned int*)alloc((size_t)EE * 4);            // 2.4 MB packed {f16 w | u16 src}
    unsigned short* W1th = (unsigned short*)alloc(128 * 128 * 2);
    unsigned short* W1tl = (unsigned short*)alloc(128 * 128 * 2);
    unsigned short* W2th = (unsigned short*)alloc(128 * 128 * 2);
    unsigned short* W2tl = (unsigned short*)alloc(128 * 128 * 2);
    unsigned short* Wmth = (unsigned short*)alloc(128 * 128 * 2);
    unsigned short* Wmtl = (unsigned short*)alloc(128 * 128 * 2);
    if (off > ws_size) return;

    // H (relu output, swizzled bf16, 12.8 MB) lives in d_out's bytes;
    // dead after gemm_pe reads it, before spmm_final writes out.
    unsigned short* H = (unsigned short*)d_out;

    // zero [counts | cursor | ssq]
    size_t zero_bytes = (size_t)((char*)ssq - (char*)counts) + 256;
    hipMemsetAsync(counts, 0, zero_bytes, stream);

    const int pre_grid  = 64 + NSLICE * FCHUNK + 2 * (NN / 16);  // 7850
    const int m2_grid   = 192 + NB_SCAN;                         // 241
    const int fill_grid = NSLICE * FCHUNK;                       // 1536
    const int gemm_grid = (NN + 31) / 32;                        // 1563
    const int spmm_grid = (NN + 7) / 8;                          // 6250

    // wmat | hist | conv2(x,emb)
    mega_pre<<<pre_grid, 256, 0, stream>>>(Fm, Wmat, ssq, edst, counts, x, emb, XS1, XS2);
    // conv_weights | scan_blocks
    mega2<<<m2_grid, 256, 0, stream>>>(W1, W2, Wmat, ssq,
                                       W1th, W1tl, W2th, W2tl, Wmth, Wmtl,
                                       counts, rs, bsum);
    scan_add<<<NB_SCAN, 256, 0, stream>>>(rs, bsum);
    // h1 = bf16(x @ W1) -> B1 (standalone: no L2 co-tenancy with fill)
    gemm_mfma<<<gemm_grid, 256, 0, stream>>>(XS1, W1th, W1tl, B1);
    // fill CSR (standalone: scatter region stays L2-resident)
    fill_kernel<<<fill_grid, 256, 0, stream>>>(esrc, edst, ew, rs, cursor, csr);
    // h = relu(A @ h1 + b1) -> H swizzled (in d_out bytes)
    spmm_relu<<<spmm_grid, 256, 0, stream>>>(B1, rs, csr, b1, H);
    // P = bf16(h @ W2 + emb @ Wm') -> B1 (row-major; h1 dead)
    gemm_pe<<<gemm_grid, 256, 0, stream>>>(H, XS2, W2th, W2tl, Wmth, Wmtl, B1, NN);
    // out = A @ P + b2
    spmm_final<<<spmm_grid, 256, 0, stream>>>(B1, rs, csr, b2, out);
}

// Round 16
// 160.737 us; speedup vs baseline: 1.2518x; 1.0193x over previous
//
#include <hip/hip_runtime.h>
#include <hip/hip_fp16.h>
#include <math.h>

#define NN 50000
#define EE 600000
#define DD 128
#define KAPPA_C 0.95f
#define EPS_C 1e-5f
#define NB_SCAN 49                                  // ceil(50000/1024)
#define NSLICE 8
#define SLICE_N ((NN + NSLICE - 1) / NSLICE)       // 6250
#define FCHUNK 192

typedef short s16x8 __attribute__((ext_vector_type(8)));   // 8 bf16 (4 VGPRs)
typedef float f32x4 __attribute__((ext_vector_type(4)));

__device__ __forceinline__ unsigned short f2bf(float f) {
    union { float f; unsigned int u; } v;
    v.f = f;
    unsigned int r = v.u + 0x7fffu + ((v.u >> 16) & 1u);
    return (unsigned short)(r >> 16);
}
__device__ __forceinline__ float bf2f(unsigned short b) {
    union { unsigned int u; float f; } v;
    v.u = ((unsigned int)b) << 16;
    return v.f;
}
// 4B CSR entry: [31:16] = f16(weight), [15:0] = u16 src  (NN=50000 < 65536)
__device__ __forceinline__ unsigned int pack_csr(int src, float w) {
    __half h = __float2half_rn(w);
    return ((unsigned int)__half_as_ushort(h) << 16) | (unsigned int)src;
}
__device__ __forceinline__ float csr_w(unsigned int v) {
    return __half2float(__ushort_as_half((unsigned short)(v >> 16)));
}
// swizzled layout, element (r, k): (r>>4)*2048 + (k>>3)*128 + (r&15)*8 + (k&7)  [shorts]

// stage 32 f32 rows (row0..row0+31, clamped) into LDS as bf16 fragment-swizzled
__device__ __forceinline__ void stage_rows(const float* __restrict__ X, int row0,
                                           unsigned short* As /* [4096] */) {
    const int tid = threadIdx.x;
    #pragma unroll
    for (int i = 0; i < 2; ++i) {
        int rl2 = (i << 4) | (tid & 15);   // 0..31 (row within tile pair)
        int kq  = tid >> 4;                 // 0..15 (8-elem k-chunk)
        int r = row0 + rl2; if (r >= NN) r = NN - 1;
        const float* xp = X + (size_t)r * 128 + kq * 8;
        float4 f0 = ((const float4*)xp)[0];
        float4 f1 = ((const float4*)xp)[1];
        union { s16x8 v; unsigned short u[8]; } cv;
        cv.u[0] = f2bf(f0.x); cv.u[1] = f2bf(f0.y); cv.u[2] = f2bf(f0.z); cv.u[3] = f2bf(f0.w);
        cv.u[4] = f2bf(f1.x); cv.u[5] = f2bf(f1.y); cv.u[6] = f2bf(f1.z); cv.u[7] = f2bf(f1.w);
        *(s16x8*)(As + (i << 11) + kq * 128 + (tid & 15) * 8) = cv.v;
    }
}

// ================ MEGA-PRE: wmat (64 blk) | hist (1536 blk) ================
__global__ __launch_bounds__(256) void mega_pre(const float* __restrict__ Fm,
                                                float* __restrict__ W,
                                                float* __restrict__ ssq,
                                                const int* __restrict__ edst,
                                                int* __restrict__ counts) {
    const int b = blockIdx.x;
    if (b < 64) {
        const int i = (b << 1) + (threadIdx.x >> 7);
        const int j = threadIdx.x & 127;
        float acc = 0.f;
        #pragma unroll 8
        for (int k = 0; k < 128; ++k)
            acc += Fm[k * 128 + i] * Fm[k * 128 + j];
        W[i * 128 + j] = acc;
        __shared__ float red[256];
        red[threadIdx.x] = acc * acc;
        __syncthreads();
        for (int o = 128; o > 0; o >>= 1) {
            if (threadIdx.x < o) red[threadIdx.x] += red[threadIdx.x + o];
            __syncthreads();
        }
        if (threadIdx.x == 0) atomicAdd(ssq, red[0]);
    } else {
        const int bb = b - 64;
        const int slice = bb & (NSLICE - 1);
        const int lo = slice * SLICE_N;
        const int hi = lo + SLICE_N;
        const int chunk = bb >> 3;
        const int per = (EE + FCHUNK - 1) / FCHUNK;
        const int e0 = chunk * per;
        int e1 = e0 + per; if (e1 > EE) e1 = EE;
        for (int e = e0 + threadIdx.x; e < e1; e += 256) {
            int d = __builtin_nontemporal_load(&edst[e]);
            if (d >= lo && d < hi) atomicAdd(&counts[d], 1);
        }
    }
}

// ================ MEGA-2: conv_weights (192 blk) | scan_blocks-256 (49 blk) ================
__global__ __launch_bounds__(256) void mega2(const float* __restrict__ W1,
                                             const float* __restrict__ W2,
                                             const float* __restrict__ Wmat,
                                             const float* __restrict__ ssq,
                                             unsigned short* __restrict__ W1th,
                                             unsigned short* __restrict__ W1tl,
                                             unsigned short* __restrict__ W2th,
                                             unsigned short* __restrict__ W2tl,
                                             unsigned short* __restrict__ Wmth,
                                             unsigned short* __restrict__ Wmtl,
                                             const int* __restrict__ counts,
                                             int* __restrict__ rs,
                                             int* __restrict__ bsum) {
    const int b = blockIdx.x;
    if (b < 192) {
        const float* M;
        unsigned short *H, *L;
        float s = 1.0f;
        if (b < 64) { M = W1; H = W1th; L = W1tl; }
        else if (b < 128) { M = W2; H = W2th; L = W2tl; }
        else {
            M = Wmat; H = Wmth; L = Wmtl;
            float n = sqrtf(*ssq);
            s = ((n > 1.0f) ? 1.0f / (n + EPS_C) : 1.0f) * KAPPA_C;
        }
        int id = (b & 63) * 256 + threadIdx.x;   // id = k*128 + c
        float v = M[id] * s;
        int k = id >> 7, c = id & 127;
        size_t o = (size_t)(c >> 4) * 2048 + (size_t)(k >> 3) * 128 + (c & 15) * 8 + (k & 7);
        unsigned short h = f2bf(v);
        H[o] = h;
        L[o] = f2bf(v - bf2f(h));
    } else {
        const int blk = b - 192;                 // 0..48
        const int tid = threadIdx.x;
        const int gid = blk * 1024 + tid * 4;
        int v0 = (gid + 0 < NN) ? counts[gid + 0] : 0;
        int v1 = (gid + 1 < NN) ? counts[gid + 1] : 0;
        int v2 = (gid + 2 < NN) ? counts[gid + 2] : 0;
        int v3 = (gid + 3 < NN) ? counts[gid + 3] : 0;
        int s0 = v0, s1 = s0 + v1, s2 = s1 + v2, s3 = s2 + v3;
        __shared__ int sd[256];
        sd[tid] = s3;
        __syncthreads();
        for (int o = 1; o < 256; o <<= 1) {
            int t = (tid >= o) ? sd[tid - o] : 0;
            __syncthreads();
            sd[tid] += t;
            __syncthreads();
        }
        int pre = (tid > 0) ? sd[tid - 1] : 0;
        if (gid + 0 < NN) rs[gid + 0] = pre;
        if (gid + 1 < NN) rs[gid + 1] = pre + s0;
        if (gid + 2 < NN) rs[gid + 2] = pre + s1;
        if (gid + 3 < NN) rs[gid + 3] = pre + s2;
        if (tid == 255) bsum[blk] = sd[255];
    }
}

// ================ scan_add (49 blk, 256 thr x 4) ================
__global__ __launch_bounds__(256) void scan_add(int* __restrict__ rs,
                                                const int* __restrict__ bsum) {
    __shared__ int pre;
    if (threadIdx.x == 0) {
        int run = 0;
        for (int i = 0; i < (int)blockIdx.x; ++i) run += bsum[i];
        pre = run;
        if (blockIdx.x == 0) rs[NN] = EE;
    }
    __syncthreads();
    int gid = blockIdx.x * 1024 + threadIdx.x * 4;
    #pragma unroll
    for (int j = 0; j < 4; ++j)
        if (gid + j < NN) rs[gid + j] += pre;
}

// ================ fill (1536 blk, 4B entries) ================
__global__ __launch_bounds__(256) void fill_kernel(const int* __restrict__ esrc,
                                                   const int* __restrict__ edst,
                                                   const float* __restrict__ ew,
                                                   const int* __restrict__ rs,
                                                   int* __restrict__ cursor,
                                                   unsigned int* __restrict__ csr) {
    const int b = blockIdx.x;
    const int slice = b & (NSLICE - 1);
    const int lo = slice * SLICE_N;
    const int hi = lo + SLICE_N;
    const int chunk = b >> 3;
    const int per = (EE + FCHUNK - 1) / FCHUNK;
    const int e0 = chunk * per;
    int e1 = e0 + per; if (e1 > EE) e1 = EE;
    for (int e = e0 + threadIdx.x; e < e1; e += 256) {
        int d = __builtin_nontemporal_load(&edst[e]);
        if (d >= lo && d < hi) {
            int pos = atomicAdd(&cursor[d], 1);
            csr[rs[d] + pos] = pack_csr(__builtin_nontemporal_load(&esrc[e]),
                                        __builtin_nontemporal_load(&ew[e]));
        }
    }
}

// ================ gemm_mfma: h1 = bf16(x @ W1); x f32 staged via LDS ================
__global__ __launch_bounds__(256, 4) void gemm_mfma(const float* __restrict__ Xf,
                                                    const unsigned short* __restrict__ Mth,
                                                    const unsigned short* __restrict__ Mtl,
                                                    unsigned short* __restrict__ outh) {
    __shared__ unsigned short As[4096];      // 32 rows x 128 k, bf16 swizzled
    const int row0 = blockIdx.x * 32;
    stage_rows(Xf, row0, As);
    __syncthreads();

    const int wave = threadIdx.x >> 6;
    const int lane = threadIdx.x & 63;
    const int col0 = wave * 32;
    const int lr = lane & 15;
    const int kg = lane >> 4;

    f32x4 acc[2][2];
    #pragma unroll
    for (int m = 0; m < 2; ++m)
        #pragma unroll
        for (int n = 0; n < 2; ++n)
            acc[m][n] = (f32x4){0.f, 0.f, 0.f, 0.f};

    #pragma unroll
    for (int k0 = 0; k0 < 128; k0 += 32) {
        const int kq = (k0 >> 3) + kg;
        s16x8 a[2];
        #pragma unroll
        for (int m = 0; m < 2; ++m)
            a[m] = *(const s16x8*)(As + (m << 11) + kq * 128 + lr * 8);
        #pragma unroll
        for (int n = 0; n < 2; ++n) {
            const size_t bo = (size_t)((col0 >> 4) + n) * 2048 + (size_t)kq * 128 + lr * 8;
            s16x8 bh = *(const s16x8*)(Mth + bo);
            s16x8 bl = *(const s16x8*)(Mtl + bo);
            #pragma unroll
            for (int m = 0; m < 2; ++m) {
                acc[m][n] = __builtin_amdgcn_mfma_f32_16x16x32_bf16(a[m], bh, acc[m][n], 0, 0, 0);
                acc[m][n] = __builtin_amdgcn_mfma_f32_16x16x32_bf16(a[m], bl, acc[m][n], 0, 0, 0);
            }
        }
    }

    #pragma unroll
    for (int m = 0; m < 2; ++m)
        #pragma unroll
        for (int n = 0; n < 2; ++n)
            #pragma unroll
            for (int j = 0; j < 4; ++j) {
                int r = row0 + m * 16 + kg * 4 + j;
                int c = col0 + n * 16 + lr;
                if (r < NN)
                    outh[(size_t)r * 128 + c] = f2bf(acc[m][n][j]);
            }
}

// ================ gemm_pe: P = bf16( H@W2 + emb@Wm' ); emb staged via LDS, H global-swizzled ================
__global__ __launch_bounds__(256, 4) void gemm_pe(const unsigned short* __restrict__ Hs,
                                                  const float* __restrict__ Ef,
                                                  const unsigned short* __restrict__ W2th,
                                                  const unsigned short* __restrict__ W2tl,
                                                  const unsigned short* __restrict__ Wmth,
                                                  const unsigned short* __restrict__ Wmtl,
                                                  unsigned short* __restrict__ P) {
    __shared__ unsigned short Es[4096];
    const int row0 = blockIdx.x * 32;
    stage_rows(Ef, row0, Es);
    __syncthreads();

    const int wave = threadIdx.x >> 6;
    const int lane = threadIdx.x & 63;
    const int col0 = wave * 32;
    const int lr = lane & 15;
    const int kg = lane >> 4;
    const int lastT = NN / 16 - 1;

    f32x4 acc[2][2];
    #pragma unroll
    for (int m = 0; m < 2; ++m)
        #pragma unroll
        for (int n = 0; n < 2; ++n)
            acc[m][n] = (f32x4){0.f, 0.f, 0.f, 0.f};

    #pragma unroll
    for (int k0 = 0; k0 < 128; k0 += 32) {
        const int kq = (k0 >> 3) + kg;
        s16x8 ah[2], ae[2];
        #pragma unroll
        for (int m = 0; m < 2; ++m) {
            int t = (row0 >> 4) + m;
            if (t > lastT) t = lastT;
            ah[m] = *(const s16x8*)(Hs + (size_t)t * 2048 + (size_t)kq * 128 + lr * 8);
            ae[m] = *(const s16x8*)(Es + (m << 11) + kq * 128 + lr * 8);
        }
        #pragma unroll
        for (int n = 0; n < 2; ++n) {
            const size_t bo = (size_t)((col0 >> 4) + n) * 2048 + (size_t)kq * 128 + lr * 8;
            s16x8 b2h = *(const s16x8*)(W2th + bo);
            s16x8 b2l = *(const s16x8*)(W2tl + bo);
            s16x8 bmh = *(const s16x8*)(Wmth + bo);
            s16x8 bml = *(const s16x8*)(Wmtl + bo);
            #pragma unroll
            for (int m = 0; m < 2; ++m) {
                acc[m][n] = __builtin_amdgcn_mfma_f32_16x16x32_bf16(ah[m], b2h, acc[m][n], 0, 0, 0);
                acc[m][n] = __builtin_amdgcn_mfma_f32_16x16x32_bf16(ah[m], b2l, acc[m][n], 0, 0, 0);
                acc[m][n] = __builtin_amdgcn_mfma_f32_16x16x32_bf16(ae[m], bmh, acc[m][n], 0, 0, 0);
                acc[m][n] = __builtin_amdgcn_mfma_f32_16x16x32_bf16(ae[m], bml, acc[m][n], 0, 0, 0);
            }
        }
    }

    #pragma unroll
    for (int m = 0; m < 2; ++m)
        #pragma unroll
        for (int n = 0; n < 2; ++n)
            #pragma unroll
            for (int j = 0; j < 4; ++j) {
                int r = row0 + m * 16 + kg * 4 + j;
                int c = col0 + n * 16 + lr;
                if (r < NN)
                    P[(size_t)r * 128 + c] = f2bf(acc[m][n][j]);
            }
}

// edge-gather step macro (32 lanes/node, 4B CSR entries)
#define GATHER4(P_, E_) \
    unsigned int p0 = csr[E_], p1 = csr[E_ + 1], p2 = csr[E_ + 2], p3 = csr[E_ + 3]; \
    ushort4 v0 = *(const ushort4*)(P_ + (size_t)(p0 & 0xffffu) * 128 + lane * 4); \
    ushort4 v1 = *(const ushort4*)(P_ + (size_t)(p1 & 0xffffu) * 128 + lane * 4); \
    ushort4 v2 = *(const ushort4*)(P_ + (size_t)(p2 & 0xffffu) * 128 + lane * 4); \
    ushort4 v3 = *(const ushort4*)(P_ + (size_t)(p3 & 0xffffu) * 128 + lane * 4); \
    float w0 = csr_w(p0), w1 = csr_w(p1); \
    float w2 = csr_w(p2), w3 = csr_w(p3); \
    acc.x += w0 * bf2f(v0.x) + w1 * bf2f(v1.x) + w2 * bf2f(v2.x) + w3 * bf2f(v3.x); \
    acc.y += w0 * bf2f(v0.y) + w1 * bf2f(v1.y) + w2 * bf2f(v2.y) + w3 * bf2f(v3.y); \
    acc.z += w0 * bf2f(v0.z) + w1 * bf2f(v1.z) + w2 * bf2f(v2.z) + w3 * bf2f(v3.z); \
    acc.w += w0 * bf2f(v0.w) + w1 * bf2f(v1.w) + w2 * bf2f(v2.w) + w3 * bf2f(v3.w);

// ================ SpMM 1: h = relu(A @ h1 + b1); SWIZZLED bf16 out; 8-deep ================
__global__ __launch_bounds__(256) void spmm_relu(const unsigned short* __restrict__ h,
                                                 const int* __restrict__ rs,
                                                 const unsigned int* __restrict__ csr,
                                                 const float* __restrict__ bias,
                                                 unsigned short* __restrict__ Hs) {
    int node = blockIdx.x * 8 + (threadIdx.x >> 5);
    int lane = threadIdx.x & 31;
    if (node >= NN) return;
    int e = rs[node];
    const int re = rs[node + 1];
    float4 acc = make_float4(0.f, 0.f, 0.f, 0.f);
    for (; e + 7 < re; e += 8) {
        { GATHER4(h, e) }
        { GATHER4(h, (e + 4)) }
    }
    for (; e + 3 < re; e += 4) {
        GATHER4(h, e)
    }
    for (; e < re; ++e) {
        unsigned int p0 = csr[e];
        float w0 = csr_w(p0);
        ushort4 v0 = *(const ushort4*)(h + (size_t)(p0 & 0xffffu) * 128 + lane * 4);
        acc.x += w0 * bf2f(v0.x); acc.y += w0 * bf2f(v0.y);
        acc.z += w0 * bf2f(v0.z); acc.w += w0 * bf2f(v0.w);
    }
    float4 b = ((const float4*)bias)[lane];
    acc.x = fmaxf(acc.x + b.x, 0.f); acc.y = fmaxf(acc.y + b.y, 0.f);
    acc.z = fmaxf(acc.z + b.z, 0.f); acc.w = fmaxf(acc.w + b.w, 0.f);
    ushort4 o;
    o.x = f2bf(acc.x); o.y = f2bf(acc.y); o.z = f2bf(acc.z); o.w = f2bf(acc.w);
    size_t so = (size_t)(node >> 4) * 2048 + (size_t)(lane >> 1) * 128
              + (node & 15) * 8 + (lane & 1) * 4;
    *(ushort4*)(Hs + so) = o;
}

// ================ final SpMM: out = A@P + b2 (f32 out); 8-deep ================
__global__ __launch_bounds__(256) void spmm_final(const unsigned short* __restrict__ P,
                                                  const int* __restrict__ rs,
                                                  const unsigned int* __restrict__ csr,
                                                  const float* __restrict__ b2,
                                                  float* __restrict__ out) {
    int node = blockIdx.x * 8 + (threadIdx.x >> 5);
    int lane = threadIdx.x & 31;
    if (node >= NN) return;
    int e = rs[node];
    const int re = rs[node + 1];
    float4 acc = make_float4(0.f, 0.f, 0.f, 0.f);
    for (; e + 7 < re; e += 8) {
        { GATHER4(P, e) }
        { GATHER4(P, (e + 4)) }
    }
    for (; e + 3 < re; e += 4) {
        GATHER4(P, e)
    }
    for (; e < re; ++e) {
        unsigned int p0 = csr[e];
        float w0 = csr_w(p0);
        ushort4 v0 = *(const ushort4*)(P + (size_t)(p0 & 0xffffu) * 128 + lane * 4);
        acc.x += w0 * bf2f(v0.x); acc.y += w0 * bf2f(v0.y);
        acc.z += w0 * bf2f(v0.z); acc.w += w0 * bf2f(v0.w);
    }
    float4 b = ((const float4*)b2)[lane];
    float4 r;
    r.x = acc.x + b.x; r.y = acc.y + b.y; r.z = acc.z + b.z; r.w = acc.w + b.w;
    ((float4*)(out + (size_t)node * 128))[lane] = r;
}

static inline size_t align_up(size_t x, size_t a) { return (x + a - 1) / a * a; }

extern "C" void kernel_launch(void* const* d_in, const int* in_sizes, int n_in,
                              void* d_out, int out_size, void* d_ws, size_t ws_size,
                              hipStream_t stream) {
    const float* x   = (const float*)d_in[0];
    const int*   esrc = (const int*)d_in[1];
    const int*   edst = (const int*)d_in[2];
    const float* ew  = (const float*)d_in[3];
    const float* W1  = (const float*)d_in[4];
    const float* b1  = (const float*)d_in[5];
    const float* W2  = (const float*)d_in[6];
    const float* b2  = (const float*)d_in[7];
    const float* Fm  = (const float*)d_in[8];
    const float* emb = (const float*)d_in[9];
    float* out = (float*)d_out;

    char* ws = (char*)d_ws;
    size_t off = 0;
    auto alloc = [&](size_t bytes) -> void* {
        void* p = ws + off;
        off = align_up(off + bytes, 256);
        return p;
    };
    unsigned short* B1  = (unsigned short*)alloc((size_t)NN * DD * 2);   // 12.8 MB: h1 row-major, then P
    float* Wmat   = (float*)alloc(128 * 128 * 4);
    int*   counts = (int*)alloc((size_t)NN * 4);
    int*   cursor = (int*)alloc((size_t)NN * 4);
    float* ssq    = (float*)alloc(256);
    int*   rs     = (int*)alloc((size_t)(NN + 1) * 4);
    int*   bsum   = (int*)alloc(64 * 4);
    unsigned int* csr = (unsigned int*)alloc((size_t)EE * 4);            // 2.4 MB packed {f16 w | u16 src}
    unsigned short* W1th = (unsigned short*)alloc(128 * 128 * 2);
    unsigned short* W1tl = (unsigned short*)alloc(128 * 128 * 2);
    unsigned short* W2th = (unsigned short*)alloc(128 * 128 * 2);
    unsigned short* W2tl = (unsigned short*)alloc(128 * 128 * 2);
    unsigned short* Wmth = (unsigned short*)alloc(128 * 128 * 2);
    unsigned short* Wmtl = (unsigned short*)alloc(128 * 128 * 2);
    if (off > ws_size) return;

    // H (relu output, swizzled bf16, 12.8 MB) lives in d_out's bytes;
    // dead after gemm_pe reads it, before spmm_final writes out.
    unsigned short* H = (unsigned short*)d_out;

    // zero [counts | cursor | ssq]
    size_t zero_bytes = (size_t)((char*)ssq - (char*)counts) + 256;
    hipMemsetAsync(counts, 0, zero_bytes, stream);

    const int pre_grid  = 64 + NSLICE * FCHUNK;                  // 1600
    const int m2_grid   = 192 + NB_SCAN;                         // 241
    const int fill_grid = NSLICE * FCHUNK;                       // 1536
    const int gemm_grid = (NN + 31) / 32;                        // 1563
    const int spmm_grid = (NN + 7) / 8;                          // 6250

    // wmat | hist
    mega_pre<<<pre_grid, 256, 0, stream>>>(Fm, Wmat, ssq, edst, counts);
    // conv_weights | scan_blocks
    mega2<<<m2_grid, 256, 0, stream>>>(W1, W2, Wmat, ssq,
                                       W1th, W1tl, W2th, W2tl, Wmth, Wmtl,
                                       counts, rs, bsum);
    scan_add<<<NB_SCAN, 256, 0, stream>>>(rs, bsum);
    // h1 = bf16(x @ W1) -> B1  (x staged f32->bf16 in LDS; conv2 eliminated)
    gemm_mfma<<<gemm_grid, 256, 0, stream>>>(x, W1th, W1tl, B1);
    // fill CSR
    fill_kernel<<<fill_grid, 256, 0, stream>>>(esrc, edst, ew, rs, cursor, csr);
    // h = relu(A @ h1 + b1) -> H swizzled (in d_out bytes)
    spmm_relu<<<spmm_grid, 256, 0, stream>>>(B1, rs, csr, b1, H);
    // P = bf16(h @ W2 + emb @ Wm') -> B1 (emb staged in LDS; h1 dead)
    gemm_pe<<<gemm_grid, 256, 0, stream>>>(H, emb, W2th, W2tl, Wmth, Wmtl, B1);
    // out = A @ P + b2
    spmm_final<<<spmm_grid, 256, 0, stream>>>(B1, rs, csr, b2, out);
}